// Round 6
// baseline (533.743 us; speedup 1.0000x reference)
//
#include <hip/hip_runtime.h>

#define TTs 50
#define NSTEP 49

using short8   = __attribute__((ext_vector_type(8))) short;
using ushort4v = __attribute__((ext_vector_type(4))) unsigned short;
using f32x4    = __attribute__((ext_vector_type(4))) float;
using int4v    = __attribute__((ext_vector_type(4))) int;

__device__ __forceinline__ unsigned short f2bf(float f) {
    unsigned u = __builtin_bit_cast(unsigned, f);
    u += 0x7FFFu + ((u >> 16) & 1u);          // RNE
    return (unsigned short)(u >> 16);
}
__device__ __forceinline__ float bf2f(unsigned short s) {
    unsigned u = ((unsigned)s) << 16;
    return __builtin_bit_cast(float, u);
}
__device__ __forceinline__ float sigm(float x)  { return 1.f / (1.f + __expf(-x)); }
__device__ __forceinline__ float ftanh(float x) { return 1.f - 2.f / (__expf(2.f * x) + 1.f); }

#define WH_SCALE 512.f
#define H_SCALE  127.f

__global__ __launch_bounds__(64)
void init_kernel(float* __restrict__ out) { if (threadIdx.x == 0) out[0] = 0.f; }

// Pack W (f32 [512][1024]):
//  y=0: Wx rows 0..255   -> Wxp bf16 [c][k] col-major frag layout
//  y=1: Wh rows 256..511 -> Wq  int8 [c][k] col-major, scaled by 512
__global__ __launch_bounds__(256)
void pack_w_kernel(const float* __restrict__ W,
                   unsigned short* __restrict__ Wxp, signed char* __restrict__ Wq)
{
    __shared__ float ld[64][65];
    const int koff = blockIdx.y * 256;
    const int k0 = (blockIdx.x & 3) * 64, c0 = (blockIdx.x >> 2) * 64;
    const int tid = threadIdx.x;
    #pragma unroll
    for (int i = 0; i < 16; ++i) {
        int idx = tid + i * 256;
        ld[idx >> 6][idx & 63] = W[(size_t)(koff + k0 + (idx >> 6)) * 1024 + c0 + (idx & 63)];
    }
    __syncthreads();
    if (blockIdx.y == 0) {
        #pragma unroll
        for (int j = 0; j < 2; ++j) {
            int idx = tid + j * 256;
            int cl = idx >> 3, kc = (idx & 7) * 8;
            short8 v;
            #pragma unroll
            for (int e = 0; e < 8; ++e) v[e] = (short)f2bf(ld[kc + e][cl]);
            *(short8*)(Wxp + (size_t)(c0 + cl) * 256 + k0 + kc) = v;
        }
    } else {
        #pragma unroll
        for (int j = 0; j < 2; ++j) {
            int idx = tid + j * 256;
            int cl = idx >> 3, kc = (idx & 7) * 8;
            unsigned long long u = 0;
            #pragma unroll
            for (int e = 0; e < 8; ++e) {
                float v = ld[kc + e][cl] * WH_SCALE;
                int q = __float2int_rn(fminf(fmaxf(v, -127.f), 127.f));
                u |= (unsigned long long)(unsigned char)(signed char)q << (8 * e);
            }
            *(unsigned long long*)(Wq + (size_t)(c0 + cl) * 256 + k0 + kc) = u;
        }
    }
}

// X projection v3: block = 64 rows of one t x 512 cols (gridDim.y=2 col halves).
// Stage gathered emb rows to LDS once; skip gather/store for dead row-groups
// (t >= len). X element offset: t*1048576 + rblk*16384 + slot*256 + L*4.
__global__ __launch_bounds__(256, 4)
void xproj_kernel(const float* __restrict__ emb,
                  const int* __restrict__ idq, const int* __restrict__ idr,
                  const int* __restrict__ lenq, const int* __restrict__ lenr,
                  const unsigned short* __restrict__ Wxp,
                  unsigned short* __restrict__ X)
{
    __shared__ __align__(16) unsigned short As[64 * 264];
    const int tid = threadIdx.x;
    const int mb = blockIdx.x * 64;
    const int t = mb >> 10, r0 = mb & 1023;
    const int ch = blockIdx.y;                 // col half: cols ch*512 ..

    // ---- stage emb -> LDS (skip rows already past their length) ----
    #pragma unroll
    for (int i = 0; i < 8; ++i) {
        int task = tid + i * 256;              // 64 rows x 32 k-chunks of 8
        int rl = task >> 5, kc = (task & 31) * 8;
        int gr = r0 + rl;
        int len = (gr < 512) ? lenq[gr] : lenr[gr - 512];
        if (t < len) {
            int id = (gr < 512) ? idq[gr * TTs + t] : idr[(gr - 512) * TTs + t];
            const float* ep = emb + (size_t)id * 256 + kc;
            float4 e0 = *(const float4*)ep;
            float4 e1 = *(const float4*)(ep + 4);
            short8 v;
            v[0] = (short)f2bf(e0.x); v[1] = (short)f2bf(e0.y);
            v[2] = (short)f2bf(e0.z); v[3] = (short)f2bf(e0.w);
            v[4] = (short)f2bf(e1.x); v[5] = (short)f2bf(e1.y);
            v[6] = (short)f2bf(e1.z); v[7] = (short)f2bf(e1.w);
            *(short8*)(As + rl * 264 + kc) = v;
        }
    }
    __syncthreads();

    const int L = tid & 63, w = tid >> 6;
    const int lanelo = L & 15, lhi = L >> 4;
    const unsigned short* arow = As + (w * 16 + lanelo) * 264 + lhi * 8;
    const unsigned short* bbase = Wxp + (size_t)(ch * 512 + lanelo) * 256 + lhi * 8;
    const int rblk = (r0 >> 4) + w;

    // liveness of the 4 rows this lane stores
    int lmax = 0;
    #pragma unroll
    for (int reg = 0; reg < 4; ++reg) {
        int gg = r0 + w * 16 + lhi * 4 + reg;
        int l = (gg < 512) ? lenq[gg] : lenr[gg - 512];
        lmax = max(lmax, l);
    }
    const bool alive = (t < lmax);

    for (int cb = 0; cb < 2; ++cb) {
        f32x4 acc[16];
        #pragma unroll
        for (int f = 0; f < 16; ++f) acc[f] = (f32x4){0.f, 0.f, 0.f, 0.f};
        #pragma unroll
        for (int ks = 0; ks < 8; ++ks) {
            short8 a = *(const short8*)(arow + ks * 32);
            #pragma unroll
            for (int f = 0; f < 16; ++f) {
                short8 b = *(const short8*)(bbase + (size_t)(cb * 256 + f * 16) * 256 + ks * 32);
                acc[f] = __builtin_amdgcn_mfma_f32_16x16x32_bf16(a, b, acc[f], 0, 0, 0);
            }
        }
        if (alive) {
            #pragma unroll
            for (int f = 0; f < 16; ++f) {
                int slot = ch * 32 + cb * 16 + f;
                size_t off = (((size_t)(t * 64 + rblk)) * 64 + slot) * 256 + L * 4;
                ushort4v v;
                v[0] = f2bf(acc[f][0]); v[1] = f2bf(acc[f][1]);
                v[2] = f2bf(acc[f][2]); v[3] = f2bf(acc[f][3]);
                *(ushort4v*)(X + off) = v;
            }
        }
    }
}

// Recurrent loop, int8 MFMA: 64 blocks x 16 rows, 16 waves.
// Wq slice register-resident (64 VGPRs). X prefetched one step ahead
// (double-buffered regs) so HBM latency hides under the previous step.
__global__ __launch_bounds__(1024, 4)
void lstm_i8_kernel(const unsigned short* __restrict__ X,
                    const signed char* __restrict__ Wq,
                    const float* __restrict__ bias,
                    const float* __restrict__ p_i, const float* __restrict__ p_f,
                    const float* __restrict__ p_o,
                    const int* __restrict__ lenq, const int* __restrict__ lenr,
                    unsigned short* __restrict__ hfin)
{
    __shared__ int hl_i[2176];                 // 2 x 16 x 272 bytes (int8 h)
    char* hlb = (char*)hl_i;
    const int tid = threadIdx.x;
    const int L = tid & 63, w = tid >> 6;      // w 0..15
    const int blk = blockIdx.x;
    const int r0g = blk * 16;
    const int lanelo = L & 15, lhi = L >> 4;
    const int hh = w * 16 + lanelo;

    for (int i = tid; i < 2176; i += 1024) hl_i[i] = 0;

    // ---- Wh slice (int8) -> registers, persistent ----
    int4v Bw[4][4];
    #pragma unroll
    for (int g = 0; g < 4; ++g)
        #pragma unroll
        for (int kc = 0; kc < 4; ++kc)
            Bw[g][kc] = *(const int4v*)(Wq + (size_t)(g * 256 + hh) * 256 + kc * 64 + lhi * 16);

    int xoff[4];
    #pragma unroll
    for (int g = 0; g < 4; ++g) xoff[g] = (g * 16 + w) * 256 + L * 4;
    const unsigned short* xb = X + (size_t)blk * 16384;

    const int ard = lanelo * 272 + lhi * 16;   // A-frag read base (bytes)
    const int awr = (lhi * 4) * 272 + hh;      // h write base (bytes)

    const float bi  = bias[hh];
    const float bj  = bias[256 + hh];
    const float bf_ = bias[512 + hh] + 2.0f;   // + FORGET_BIAS
    const float bo  = bias[768 + hh];
    const float pii = p_i[hh], pff = p_f[hh], poo = p_o[hh];
    const float INV = 1.f / (H_SCALE * WH_SCALE);

    int len_[4];
    #pragma unroll
    for (int reg = 0; reg < 4; ++reg) {
        int gr = r0g + lhi * 4 + reg;
        len_[reg] = (gr < 512) ? lenq[gr] : lenr[gr - 512];
    }
    const int maxlen = max(max(len_[0], len_[1]), max(len_[2], len_[3]));

    float cst[4] = {};
    unsigned short hreg[4] = {};

    // preload X for t = 0 (maxlen >= 1 always)
    ushort4v xr[4], xn[4];
    #pragma unroll
    for (int g = 0; g < 4; ++g) xr[g] = *(const ushort4v*)(xb + xoff[g]);

    __syncthreads();

    for (int t = 0; t < NSTEP; ++t) {
        const int rb = (t & 1) * 4352;
        const int wb = 4352 - rb;

        // prefetch next step's x (dead groups never load; values unused)
        if (t + 1 < maxlen) {
            const unsigned short* xt1 = xb + (size_t)(t + 1) * 1048576;
            #pragma unroll
            for (int g = 0; g < 4; ++g) xn[g] = *(const ushort4v*)(xt1 + xoff[g]);
        }

        int4v acc[4];
        #pragma unroll
        for (int g = 0; g < 4; ++g) acc[g] = (int4v){0, 0, 0, 0};

        #pragma unroll
        for (int kc = 0; kc < 4; ++kc) {
            int4v a = *(const int4v*)(hlb + rb + ard + kc * 64);
            #pragma unroll
            for (int g = 0; g < 4; ++g)
                acc[g] = __builtin_amdgcn_mfma_i32_16x16x64_i8(a, Bw[g][kc], acc[g], 0, 0, 0);
        }

        #pragma unroll
        for (int reg = 0; reg < 4; ++reg) {
            float cv = cst[reg];
            float zi = (float)acc[0][reg] * INV + bf2f(xr[0][reg]) + bi;
            float zj = (float)acc[1][reg] * INV + bf2f(xr[1][reg]) + bj;
            float zf = (float)acc[2][reg] * INV + bf2f(xr[2][reg]) + bf_;
            float zo = (float)acc[3][reg] * INV + bf2f(xr[3][reg]) + bo;
            float iv = sigm(zi + pii * cv);
            float fv = sigm(zf + pff * cv);
            float jv = ftanh(zj);
            float cn = fv * cv + iv * jv;
            float ov = sigm(zo + poo * cn);
            float hn = ov * ftanh(cn);
            bool upd = (t < len_[reg]);
            float hsel = upd ? hn : bf2f(hreg[reg]);
            if (upd) cst[reg] = cn;
            hreg[reg] = f2bf(hsel);
            float hq = bf2f(hreg[reg]);        // quantize the bf16-rounded value
            hlb[wb + awr + reg * 272] = (signed char)__float2int_rn(hq * H_SCALE);
        }
        __syncthreads();
        #pragma unroll
        for (int g = 0; g < 4; ++g) xr[g] = xn[g];
    }

    #pragma unroll
    for (int reg = 0; reg < 4; ++reg)
        hfin[(size_t)(r0g + lhi * 4 + reg) * 256 + hh] = hreg[reg];
}

#define TS 64
#define KT 16
#define LDW (TS + 4)

// qM[512x256] = bf16 h(rows 0..511) @ fp32 M[256x256]
__global__ __launch_bounds__(256)
void gemm_qM_kernel(const unsigned short* __restrict__ hA, const float* __restrict__ B,
                    float* __restrict__ C)
{
    __shared__ float As[KT][LDW];
    __shared__ float Bs[KT][LDW];
    const int tid = threadIdx.x;
    const int tx = tid & 15, ty = tid >> 4;
    const int m0 = blockIdx.x * TS, n0 = blockIdx.y * TS;
    float acc[4][4] = {};
    for (int kk = 0; kk < 256; kk += KT) {
        #pragma unroll
        for (int i = 0; i < 4; ++i) {
            int l = tid + i * 256;
            As[l & 15][l >> 4] = bf2f(hA[(m0 + (l >> 4)) * 256 + kk + (l & 15)]);
            Bs[l >> 6][l & 63] = B[(kk + (l >> 6)) * 256 + n0 + (l & 63)];
        }
        __syncthreads();
        #pragma unroll
        for (int k = 0; k < KT; ++k) {
            float4 a4 = *(const float4*)&As[k][ty * 4];
            float4 b4 = *(const float4*)&Bs[k][tx * 4];
            float av[4] = {a4.x, a4.y, a4.z, a4.w};
            float bv[4] = {b4.x, b4.y, b4.z, b4.w};
            #pragma unroll
            for (int i = 0; i < 4; ++i)
                #pragma unroll
                for (int j = 0; j < 4; ++j)
                    acc[i][j] = fmaf(av[i], bv[j], acc[i][j]);
        }
        __syncthreads();
    }
    #pragma unroll
    for (int i = 0; i < 4; ++i) {
        float4 v = {acc[i][0], acc[i][1], acc[i][2], acc[i][3]};
        *(float4*)&C[(m0 + ty * 4 + i) * 256 + n0 + tx * 4] = v;
    }
}

// D[512x512] = fp32 qM[512x256] @ (bf16 r[512x256])^T
__global__ __launch_bounds__(256)
void gemm_D_kernel(const float* __restrict__ A, const unsigned short* __restrict__ hB,
                   float* __restrict__ C)
{
    __shared__ float As[KT][LDW];
    __shared__ float Bs[KT][LDW];
    const int tid = threadIdx.x;
    const int tx = tid & 15, ty = tid >> 4;
    const int m0 = blockIdx.x * TS, n0 = blockIdx.y * TS;
    float acc[4][4] = {};
    for (int kk = 0; kk < 256; kk += KT) {
        #pragma unroll
        for (int i = 0; i < 4; ++i) {
            int l = tid + i * 256;
            As[l & 15][l >> 4] = A[(m0 + (l >> 4)) * 256 + kk + (l & 15)];
            Bs[l & 15][l >> 4] = bf2f(hB[(n0 + (l >> 4)) * 256 + kk + (l & 15)]);
        }
        __syncthreads();
        #pragma unroll
        for (int k = 0; k < KT; ++k) {
            float4 a4 = *(const float4*)&As[k][ty * 4];
            float4 b4 = *(const float4*)&Bs[k][tx * 4];
            float av[4] = {a4.x, a4.y, a4.z, a4.w};
            float bv[4] = {b4.x, b4.y, b4.z, b4.w};
            #pragma unroll
            for (int i = 0; i < 4; ++i)
                #pragma unroll
                for (int j = 0; j < 4; ++j)
                    acc[i][j] = fmaf(av[i], bv[j], acc[i][j]);
        }
        __syncthreads();
    }
    #pragma unroll
    for (int i = 0; i < 4; ++i) {
        float4 v = {acc[i][0], acc[i][1], acc[i][2], acc[i][3]};
        *(float4*)&C[(m0 + ty * 4 + i) * 512 + n0 + tx * 4] = v;
    }
}

__global__ __launch_bounds__(256)
void loss_kernel(const float* __restrict__ D, const float* __restrict__ wd,
                 float* __restrict__ out)
{
    int idx = blockIdx.x * 256 + threadIdx.x;
    int j = idx & 511;
    float d   = D[idx];
    float pos = D[j * 512 + j];
    float ww  = wd[idx];
    float wp  = wd[j * 512 + j];
    float wn  = fmaxf(0.f, ww / wp - 1.f);
    float v   = fmaxf(0.f, d - pos + wn);
    #pragma unroll
    for (int o = 32; o > 0; o >>= 1) v += __shfl_down(v, o);
    __shared__ float sm[4];
    if ((threadIdx.x & 63) == 0) sm[threadIdx.x >> 6] = v;
    __syncthreads();
    if (threadIdx.x == 0) atomicAdd(out, sm[0] + sm[1] + sm[2] + sm[3]);
}

extern "C" void kernel_launch(void* const* d_in, const int* in_sizes, int n_in,
                              void* d_out, int out_size, void* d_ws, size_t ws_size,
                              hipStream_t stream) {
    const int*   idq  = (const int*)d_in[0];
    const int*   idr  = (const int*)d_in[1];
    const int*   lenq = (const int*)d_in[2];
    const int*   lenr = (const int*)d_in[3];
    const float* wd   = (const float*)d_in[4];
    const float* emb  = (const float*)d_in[5];
    const float* W    = (const float*)d_in[6];
    const float* bias = (const float*)d_in[7];
    const float* p_i  = (const float*)d_in[8];
    const float* p_f  = (const float*)d_in[9];
    const float* p_o  = (const float*)d_in[10];
    const float* Mm   = (const float*)d_in[11];
    float* out = (float*)d_out;

    char* ws = (char*)d_ws;
    unsigned short* X    = (unsigned short*)ws;           // 49*1024*1024 bf16 = 102,760,448 B
    char* p = ws + (size_t)NSTEP * 1048576 * 2;
    unsigned short* hfin = (unsigned short*)p;  p += 1024 * 256 * 2;   // 512 KB
    unsigned short* Wxp  = (unsigned short*)p;  p += 1024 * 256 * 2;   // 512 KB
    signed char*    Wq   = (signed char*)p;     p += 1024 * 256;       // 256 KB
    float* qM = (float*)p;  p += 512 * 256 * 4;                        // 512 KB
    float* D  = (float*)p;                                             // 1 MB

    init_kernel<<<1, 64, 0, stream>>>(out);
    pack_w_kernel<<<dim3(64, 2), 256, 0, stream>>>(W, Wxp, Wq);
    xproj_kernel<<<dim3(784, 2), 256, 0, stream>>>(emb, idq, idr, lenq, lenr, Wxp, X);
    lstm_i8_kernel<<<64, 1024, 0, stream>>>(X, Wq, bias, p_i, p_f, p_o,
                                            lenq, lenr, hfin);
    gemm_qM_kernel<<<dim3(8, 4), 256, 0, stream>>>(hfin, Mm, qM);
    gemm_D_kernel<<<dim3(8, 8), 256, 0, stream>>>(qM, hfin + 512 * 256, D);
    loss_kernel<<<1024, 256, 0, stream>>>(D, wd, out);
}

// Round 7
// 274.212 us; speedup vs baseline: 1.9465x; 1.9465x over previous
//
#include <hip/hip_runtime.h>

#define TTs 50
#define NSTEP 49

using short8   = __attribute__((ext_vector_type(8))) short;
using ushort4v = __attribute__((ext_vector_type(4))) unsigned short;
using f32x4    = __attribute__((ext_vector_type(4))) float;
using int4v    = __attribute__((ext_vector_type(4))) int;

__device__ __forceinline__ unsigned short f2bf(float f) {
    unsigned u = __builtin_bit_cast(unsigned, f);
    u += 0x7FFFu + ((u >> 16) & 1u);          // RNE
    return (unsigned short)(u >> 16);
}
__device__ __forceinline__ float bf2f(unsigned short s) {
    unsigned u = ((unsigned)s) << 16;
    return __builtin_bit_cast(float, u);
}
__device__ __forceinline__ float sigm(float x)  { return 1.f / (1.f + __expf(-x)); }
__device__ __forceinline__ float ftanh(float x) { return 1.f - 2.f / (__expf(2.f * x) + 1.f); }

#define WH_SCALE 512.f
#define H_SCALE  127.f

__global__ __launch_bounds__(64)
void init_kernel(float* __restrict__ out) { if (threadIdx.x == 0) out[0] = 0.f; }

// Pack W (f32 [512][1024]):
//  y=0: Wx rows 0..255   -> Wxp bf16 [c][k] col-major frag layout
//  y=1: Wh rows 256..511 -> Wq  int8 [c][k] col-major, scaled by 512
__global__ __launch_bounds__(256)
void pack_w_kernel(const float* __restrict__ W,
                   unsigned short* __restrict__ Wxp, signed char* __restrict__ Wq)
{
    __shared__ float ld[64][65];
    const int koff = blockIdx.y * 256;
    const int k0 = (blockIdx.x & 3) * 64, c0 = (blockIdx.x >> 2) * 64;
    const int tid = threadIdx.x;
    #pragma unroll
    for (int i = 0; i < 16; ++i) {
        int idx = tid + i * 256;
        ld[idx >> 6][idx & 63] = W[(size_t)(koff + k0 + (idx >> 6)) * 1024 + c0 + (idx & 63)];
    }
    __syncthreads();
    if (blockIdx.y == 0) {
        #pragma unroll
        for (int j = 0; j < 2; ++j) {
            int idx = tid + j * 256;
            int cl = idx >> 3, kc = (idx & 7) * 8;
            short8 v;
            #pragma unroll
            for (int e = 0; e < 8; ++e) v[e] = (short)f2bf(ld[kc + e][cl]);
            *(short8*)(Wxp + (size_t)(c0 + cl) * 256 + k0 + kc) = v;
        }
    } else {
        #pragma unroll
        for (int j = 0; j < 2; ++j) {
            int idx = tid + j * 256;
            int cl = idx >> 3, kc = (idx & 7) * 8;
            unsigned long long u = 0;
            #pragma unroll
            for (int e = 0; e < 8; ++e) {
                float v = ld[kc + e][cl] * WH_SCALE;
                int q = __float2int_rn(fminf(fmaxf(v, -127.f), 127.f));
                u |= (unsigned long long)(unsigned char)(signed char)q << (8 * e);
            }
            *(unsigned long long*)(Wq + (size_t)(c0 + cl) * 256 + k0 + kc) = u;
        }
    }
}

// X projection v4: Wx REGISTER-RESIDENT. Block = 512 thr (8 waves) owns a
// 256-col slice (blockIdx.y of 4); wave owns 32 cols = 2 B-frags x 8 ks = 64
// VGPR, loaded ONCE. Block sweeps 4 row-tiles of 64 rows (grid-stride by 196).
// Bias (+FORGET_BIAS) folded into the stored X.
// X element offset: t*1048576 + rblk*16384 + slot*256 + L*4  (slot = zcol/16)
__global__ __launch_bounds__(512, 4)
void xproj_kernel(const float* __restrict__ emb,
                  const int* __restrict__ idq, const int* __restrict__ idr,
                  const int* __restrict__ lenq, const int* __restrict__ lenr,
                  const unsigned short* __restrict__ Wxp,
                  const float* __restrict__ bias,
                  unsigned short* __restrict__ X)
{
    __shared__ __align__(16) unsigned short As[64 * 264];   // 33 KB
    __shared__ int Ls2[4][64];
    __shared__ int Ids2[4][64];

    const int tid = threadIdx.x;
    const int L = tid & 63, w = tid >> 6;          // 8 waves
    const int lanelo = L & 15, lhi = L >> 4;
    const int cslice = blockIdx.y;                 // 0..3
    const int colbase = cslice * 256 + w * 32;     // wave's 32 cols
    const int slot0 = cslice * 16 + w * 2;

    // ---- Wx slice -> registers (persistent) ----
    short8 Bx[2][8];
    #pragma unroll
    for (int cf = 0; cf < 2; ++cf) {
        const unsigned short* bb = Wxp + (size_t)(colbase + cf * 16 + lanelo) * 256 + lhi * 8;
        #pragma unroll
        for (int ks = 0; ks < 8; ++ks) Bx[cf][ks] = *(const short8*)(bb + ks * 32);
    }
    // per-lane bias for the two owned cols (incl. forget bias on gate 2)
    float bc[2];
    #pragma unroll
    for (int cf = 0; cf < 2; ++cf) {
        int col = colbase + cf * 16 + lanelo;
        bc[cf] = bias[col] + ((col >= 512 && col < 768) ? 2.0f : 0.f);
    }

    // ---- stage lens/ids for this block's 4 row-tiles ----
    if (tid < 256) {
        int it = tid >> 6, rl = tid & 63;
        int rt = blockIdx.x + it * 196;
        int t = rt >> 4, r0 = (rt & 15) * 64;
        int gr = r0 + rl;
        Ls2[it][rl] = (gr < 512) ? lenq[gr] : lenr[gr - 512];
        Ids2[it][rl] = (gr < 512) ? idq[gr * TTs + t] : idr[(gr - 512) * TTs + t];
    }
    __syncthreads();

    for (int it = 0; it < 4; ++it) {
        const int rt = blockIdx.x + it * 196;
        const int t = rt >> 4;
        const int rblkb = (rt & 15) * 4;
        const int* Ls = Ls2[it];
        const int* Ids = Ids2[it];

        // ---- stage gathered emb rows -> LDS (bf16), skip dead rows ----
        float4 ev0[4], ev1[4];
        bool live[4];
        #pragma unroll
        for (int i = 0; i < 4; ++i) {
            int task = tid + i * 512;
            int rl = task >> 5, kc = (task & 31) * 8;
            live[i] = (t < Ls[rl]);
            if (live[i]) {
                const float* ep = emb + (size_t)Ids[rl] * 256 + kc;
                ev0[i] = *(const float4*)ep;
                ev1[i] = *(const float4*)(ep + 4);
            }
        }
        #pragma unroll
        for (int i = 0; i < 4; ++i) {
            if (live[i]) {
                int task = tid + i * 512;
                int rl = task >> 5, kc = (task & 31) * 8;
                short8 v;
                v[0] = (short)f2bf(ev0[i].x); v[1] = (short)f2bf(ev0[i].y);
                v[2] = (short)f2bf(ev0[i].z); v[3] = (short)f2bf(ev0[i].w);
                v[4] = (short)f2bf(ev1[i].x); v[5] = (short)f2bf(ev1[i].y);
                v[6] = (short)f2bf(ev1[i].z); v[7] = (short)f2bf(ev1[i].w);
                *(short8*)(As + rl * 264 + kc) = v;
            }
        }
        __syncthreads();

        // ---- compute: 4 row-groups x (8 ds_read + 16 MFMA) ----
        #pragma unroll
        for (int rg = 0; rg < 4; ++rg) {
            int base = rg * 16 + lhi * 4;
            int lmax = max(max(Ls[base], Ls[base + 1]), max(Ls[base + 2], Ls[base + 3]));
            bool myalive = (t < lmax);
            if (__any(myalive)) {
                f32x4 a0 = (f32x4){0.f, 0.f, 0.f, 0.f};
                f32x4 a1 = (f32x4){0.f, 0.f, 0.f, 0.f};
                const unsigned short* ar = As + (rg * 16 + lanelo) * 264 + lhi * 8;
                #pragma unroll
                for (int ks = 0; ks < 8; ++ks) {
                    short8 a = *(const short8*)(ar + ks * 32);
                    a0 = __builtin_amdgcn_mfma_f32_16x16x32_bf16(a, Bx[0][ks], a0, 0, 0, 0);
                    a1 = __builtin_amdgcn_mfma_f32_16x16x32_bf16(a, Bx[1][ks], a1, 0, 0, 0);
                }
                if (myalive) {
                    size_t off = (((size_t)(t * 64 + rblkb + rg)) * 64 + slot0) * 256 + L * 4;
                    ushort4v v0, v1;
                    #pragma unroll
                    for (int j = 0; j < 4; ++j) {
                        v0[j] = f2bf(a0[j] + bc[0]);
                        v1[j] = f2bf(a1[j] + bc[1]);
                    }
                    *(ushort4v*)(X + off) = v0;
                    *(ushort4v*)(X + off + 256) = v1;
                }
            }
        }
        __syncthreads();   // protect As/Ls before next tile's staging
    }
}

// Recurrent loop, int8 MFMA: 64 blocks x 16 rows, 16 waves.
// Wq slice register-resident (64 VGPRs). X prefetched one step ahead with a
// wave-uniform CLAMPED address (no divergence; stale values masked at use).
// Bias is already folded into X.
__global__ __launch_bounds__(1024, 4)
void lstm_i8_kernel(const unsigned short* __restrict__ X,
                    const signed char* __restrict__ Wq,
                    const float* __restrict__ p_i, const float* __restrict__ p_f,
                    const float* __restrict__ p_o,
                    const int* __restrict__ lenq, const int* __restrict__ lenr,
                    unsigned short* __restrict__ hfin)
{
    __shared__ int hl_i[2176];                 // 2 x 16 x 272 bytes (int8 h)
    char* hlb = (char*)hl_i;
    const int tid = threadIdx.x;
    const int L = tid & 63, w = tid >> 6;      // w 0..15
    const int blk = blockIdx.x;
    const int r0g = blk * 16;
    const int lanelo = L & 15, lhi = L >> 4;
    const int hh = w * 16 + lanelo;

    for (int i = tid; i < 2176; i += 1024) hl_i[i] = 0;

    // ---- Wh slice (int8) -> registers, persistent ----
    int4v Bw[4][4];
    #pragma unroll
    for (int g = 0; g < 4; ++g)
        #pragma unroll
        for (int kc = 0; kc < 4; ++kc)
            Bw[g][kc] = *(const int4v*)(Wq + (size_t)(g * 256 + hh) * 256 + kc * 64 + lhi * 16);

    int xoff[4];
    #pragma unroll
    for (int g = 0; g < 4; ++g) xoff[g] = (g * 16 + w) * 256 + L * 4;
    const unsigned short* xb = X + (size_t)blk * 16384;

    const int ard = lanelo * 272 + lhi * 16;   // A-frag read base (bytes)
    const int awr = (lhi * 4) * 272 + hh;      // h write base (bytes)

    const float pii = p_i[hh], pff = p_f[hh], poo = p_o[hh];
    const float INV = 1.f / (H_SCALE * WH_SCALE);

    int len_[4];
    #pragma unroll
    for (int reg = 0; reg < 4; ++reg) {
        int gr = r0g + lhi * 4 + reg;
        len_[reg] = (gr < 512) ? lenq[gr] : lenr[gr - 512];
    }

    float cst[4] = {};
    unsigned short hreg[4] = {};

    // preload X for t = 0 (len >= 1 always => written)
    ushort4v xr[4], xn[4];
    #pragma unroll
    for (int g = 0; g < 4; ++g) xr[g] = *(const ushort4v*)(xb + xoff[g]);

    __syncthreads();

    for (int t = 0; t < NSTEP; ++t) {
        const int rb = (t & 1) * 4352;
        const int wb = 4352 - rb;

        // unconditional clamped prefetch: wave-uniform address, no divergence.
        // (slots past a row's length may hold stale/poison bf16 -> finite,
        //  and are discarded by the t<len mask below.)
        const int tn = (t + 1 < NSTEP) ? t + 1 : NSTEP - 1;
        const unsigned short* xt1 = xb + (size_t)tn * 1048576;
        #pragma unroll
        for (int g = 0; g < 4; ++g) xn[g] = *(const ushort4v*)(xt1 + xoff[g]);

        int4v acc[4];
        #pragma unroll
        for (int g = 0; g < 4; ++g) acc[g] = (int4v){0, 0, 0, 0};

        #pragma unroll
        for (int kc = 0; kc < 4; ++kc) {
            int4v a = *(const int4v*)(hlb + rb + ard + kc * 64);
            #pragma unroll
            for (int g = 0; g < 4; ++g)
                acc[g] = __builtin_amdgcn_mfma_i32_16x16x64_i8(a, Bw[g][kc], acc[g], 0, 0, 0);
        }

        #pragma unroll
        for (int reg = 0; reg < 4; ++reg) {
            float cv = cst[reg];
            float zi = fmaf((float)acc[0][reg], INV, bf2f(xr[0][reg]));
            float zj = fmaf((float)acc[1][reg], INV, bf2f(xr[1][reg]));
            float zf = fmaf((float)acc[2][reg], INV, bf2f(xr[2][reg]));
            float zo = fmaf((float)acc[3][reg], INV, bf2f(xr[3][reg]));
            float iv = sigm(fmaf(pii, cv, zi));
            float fv = sigm(fmaf(pff, cv, zf));
            float jv = ftanh(zj);
            float cn = fv * cv + iv * jv;
            float ov = sigm(fmaf(poo, cn, zo));
            float hn = ov * ftanh(cn);
            bool upd = (t < len_[reg]);
            float hsel = upd ? hn : bf2f(hreg[reg]);
            if (upd) cst[reg] = cn;
            hreg[reg] = f2bf(hsel);
            float hq = bf2f(hreg[reg]);        // quantize the bf16-rounded value
            hlb[wb + awr + reg * 272] = (signed char)__float2int_rn(hq * H_SCALE);
        }
        __syncthreads();
        #pragma unroll
        for (int g = 0; g < 4; ++g) xr[g] = xn[g];
    }

    #pragma unroll
    for (int reg = 0; reg < 4; ++reg)
        hfin[(size_t)(r0g + lhi * 4 + reg) * 256 + hh] = hreg[reg];
}

#define TS 64
#define KT 16
#define LDW (TS + 4)

// qM[512x256] = bf16 h(rows 0..511) @ fp32 M[256x256]
__global__ __launch_bounds__(256)
void gemm_qM_kernel(const unsigned short* __restrict__ hA, const float* __restrict__ B,
                    float* __restrict__ C)
{
    __shared__ float As[KT][LDW];
    __shared__ float Bs[KT][LDW];
    const int tid = threadIdx.x;
    const int tx = tid & 15, ty = tid >> 4;
    const int m0 = blockIdx.x * TS, n0 = blockIdx.y * TS;
    float acc[4][4] = {};
    for (int kk = 0; kk < 256; kk += KT) {
        #pragma unroll
        for (int i = 0; i < 4; ++i) {
            int l = tid + i * 256;
            As[l & 15][l >> 4] = bf2f(hA[(m0 + (l >> 4)) * 256 + kk + (l & 15)]);
            Bs[l >> 6][l & 63] = B[(kk + (l >> 6)) * 256 + n0 + (l & 63)];
        }
        __syncthreads();
        #pragma unroll
        for (int k = 0; k < KT; ++k) {
            float4 a4 = *(const float4*)&As[k][ty * 4];
            float4 b4 = *(const float4*)&Bs[k][tx * 4];
            float av[4] = {a4.x, a4.y, a4.z, a4.w};
            float bv[4] = {b4.x, b4.y, b4.z, b4.w};
            #pragma unroll
            for (int i = 0; i < 4; ++i)
                #pragma unroll
                for (int j = 0; j < 4; ++j)
                    acc[i][j] = fmaf(av[i], bv[j], acc[i][j]);
        }
        __syncthreads();
    }
    #pragma unroll
    for (int i = 0; i < 4; ++i) {
        float4 v = {acc[i][0], acc[i][1], acc[i][2], acc[i][3]};
        *(float4*)&C[(m0 + ty * 4 + i) * 256 + n0 + tx * 4] = v;
    }
}

// D[512x512] = fp32 qM[512x256] @ (bf16 r[512x256])^T
__global__ __launch_bounds__(256)
void gemm_D_kernel(const float* __restrict__ A, const unsigned short* __restrict__ hB,
                   float* __restrict__ C)
{
    __shared__ float As[KT][LDW];
    __shared__ float Bs[KT][LDW];
    const int tid = threadIdx.x;
    const int tx = tid & 15, ty = tid >> 4;
    const int m0 = blockIdx.x * TS, n0 = blockIdx.y * TS;
    float acc[4][4] = {};
    for (int kk = 0; kk < 256; kk += KT) {
        #pragma unroll
        for (int i = 0; i < 4; ++i) {
            int l = tid + i * 256;
            As[l & 15][l >> 4] = A[(m0 + (l >> 4)) * 256 + kk + (l & 15)];
            Bs[l & 15][l >> 4] = bf2f(hB[(n0 + (l >> 4)) * 256 + kk + (l & 15)]);
        }
        __syncthreads();
        #pragma unroll
        for (int k = 0; k < KT; ++k) {
            float4 a4 = *(const float4*)&As[k][ty * 4];
            float4 b4 = *(const float4*)&Bs[k][tx * 4];
            float av[4] = {a4.x, a4.y, a4.z, a4.w};
            float bv[4] = {b4.x, b4.y, b4.z, b4.w};
            #pragma unroll
            for (int i = 0; i < 4; ++i)
                #pragma unroll
                for (int j = 0; j < 4; ++j)
                    acc[i][j] = fmaf(av[i], bv[j], acc[i][j]);
        }
        __syncthreads();
    }
    #pragma unroll
    for (int i = 0; i < 4; ++i) {
        float4 v = {acc[i][0], acc[i][1], acc[i][2], acc[i][3]};
        *(float4*)&C[(m0 + ty * 4 + i) * 512 + n0 + tx * 4] = v;
    }
}

__global__ __launch_bounds__(256)
void loss_kernel(const float* __restrict__ D, const float* __restrict__ wd,
                 float* __restrict__ out)
{
    int idx = blockIdx.x * 256 + threadIdx.x;
    int j = idx & 511;
    float d   = D[idx];
    float pos = D[j * 512 + j];
    float ww  = wd[idx];
    float wp  = wd[j * 512 + j];
    float wn  = fmaxf(0.f, ww / wp - 1.f);
    float v   = fmaxf(0.f, d - pos + wn);
    #pragma unroll
    for (int o = 32; o > 0; o >>= 1) v += __shfl_down(v, o);
    __shared__ float sm[4];
    if ((threadIdx.x & 63) == 0) sm[threadIdx.x >> 6] = v;
    __syncthreads();
    if (threadIdx.x == 0) atomicAdd(out, sm[0] + sm[1] + sm[2] + sm[3]);
}

extern "C" void kernel_launch(void* const* d_in, const int* in_sizes, int n_in,
                              void* d_out, int out_size, void* d_ws, size_t ws_size,
                              hipStream_t stream) {
    const int*   idq  = (const int*)d_in[0];
    const int*   idr  = (const int*)d_in[1];
    const int*   lenq = (const int*)d_in[2];
    const int*   lenr = (const int*)d_in[3];
    const float* wd   = (const float*)d_in[4];
    const float* emb  = (const float*)d_in[5];
    const float* W    = (const float*)d_in[6];
    const float* bias = (const float*)d_in[7];
    const float* p_i  = (const float*)d_in[8];
    const float* p_f  = (const float*)d_in[9];
    const float* p_o  = (const float*)d_in[10];
    const float* Mm   = (const float*)d_in[11];
    float* out = (float*)d_out;

    char* ws = (char*)d_ws;
    unsigned short* X    = (unsigned short*)ws;           // 49*1024*1024 bf16 = 102,760,448 B
    char* p = ws + (size_t)NSTEP * 1048576 * 2;
    unsigned short* hfin = (unsigned short*)p;  p += 1024 * 256 * 2;   // 512 KB
    unsigned short* Wxp  = (unsigned short*)p;  p += 1024 * 256 * 2;   // 512 KB
    signed char*    Wq   = (signed char*)p;     p += 1024 * 256;       // 256 KB
    float* qM = (float*)p;  p += 512 * 256 * 4;                        // 512 KB
    float* D  = (float*)p;                                             // 1 MB

    init_kernel<<<1, 64, 0, stream>>>(out);
    pack_w_kernel<<<dim3(64, 2), 256, 0, stream>>>(W, Wxp, Wq);
    xproj_kernel<<<dim3(196, 4), 512, 0, stream>>>(emb, idq, idr, lenq, lenr,
                                                   Wxp, bias, X);
    lstm_i8_kernel<<<64, 1024, 0, stream>>>(X, Wq, p_i, p_f, p_o,
                                            lenq, lenr, hfin);
    gemm_qM_kernel<<<dim3(8, 4), 256, 0, stream>>>(hfin, Mm, qM);
    gemm_D_kernel<<<dim3(8, 8), 256, 0, stream>>>(qM, hfin + 512 * 256, D);
    loss_kernel<<<1024, 256, 0, stream>>>(D, wd, out);
}

// Round 8
// 204.887 us; speedup vs baseline: 2.6051x; 1.3384x over previous
//
#include <hip/hip_runtime.h>

#define TTs 50
#define NSTEP 49

using short8   = __attribute__((ext_vector_type(8))) short;
using ushort4v = __attribute__((ext_vector_type(4))) unsigned short;
using f32x4    = __attribute__((ext_vector_type(4))) float;
using int4v    = __attribute__((ext_vector_type(4))) int;

__device__ __forceinline__ unsigned short f2bf(float f) {
    unsigned u = __builtin_bit_cast(unsigned, f);
    u += 0x7FFFu + ((u >> 16) & 1u);          // RNE
    return (unsigned short)(u >> 16);
}
__device__ __forceinline__ float bf2f(unsigned short s) {
    unsigned u = ((unsigned)s) << 16;
    return __builtin_bit_cast(float, u);
}
__device__ __forceinline__ float sigm(float x)  { return 1.f / (1.f + __expf(-x)); }
__device__ __forceinline__ float ftanh(float x) { return 1.f - 2.f / (__expf(2.f * x) + 1.f); }

#define WH_SCALE 512.f
#define H_SCALE  127.f

__global__ __launch_bounds__(64)
void init_kernel(float* __restrict__ out) { if (threadIdx.x == 0) out[0] = 0.f; }

// Pack W (f32 [512][1024]):
//  y=0: Wx rows 0..255   -> Wxp bf16 [c][k] col-major frag layout
//  y=1: Wh rows 256..511 -> Wq  int8 [c][k] col-major, scaled by 512
__global__ __launch_bounds__(256)
void pack_w_kernel(const float* __restrict__ W,
                   unsigned short* __restrict__ Wxp, signed char* __restrict__ Wq)
{
    __shared__ float ld[64][65];
    const int koff = blockIdx.y * 256;
    const int k0 = (blockIdx.x & 3) * 64, c0 = (blockIdx.x >> 2) * 64;
    const int tid = threadIdx.x;
    #pragma unroll
    for (int i = 0; i < 16; ++i) {
        int idx = tid + i * 256;
        ld[idx >> 6][idx & 63] = W[(size_t)(koff + k0 + (idx >> 6)) * 1024 + c0 + (idx & 63)];
    }
    __syncthreads();
    if (blockIdx.y == 0) {
        #pragma unroll
        for (int j = 0; j < 2; ++j) {
            int idx = tid + j * 256;
            int cl = idx >> 3, kc = (idx & 7) * 8;
            short8 v;
            #pragma unroll
            for (int e = 0; e < 8; ++e) v[e] = (short)f2bf(ld[kc + e][cl]);
            *(short8*)(Wxp + (size_t)(c0 + cl) * 256 + k0 + kc) = v;
        }
    } else {
        #pragma unroll
        for (int j = 0; j < 2; ++j) {
            int idx = tid + j * 256;
            int cl = idx >> 3, kc = (idx & 7) * 8;
            unsigned long long u = 0;
            #pragma unroll
            for (int e = 0; e < 8; ++e) {
                float v = ld[kc + e][cl] * WH_SCALE;
                int q = __float2int_rn(fminf(fmaxf(v, -127.f), 127.f));
                u |= (unsigned long long)(unsigned char)(signed char)q << (8 * e);
            }
            *(unsigned long long*)(Wq + (size_t)(c0 + cl) * 256 + k0 + kc) = u;
        }
    }
}

// X projection v4 (unchanged): Wx register-resident; block = 512 thr owns a
// 256-col slice (blockIdx.y of 4); sweeps 4 row-tiles. Bias folded into X.
// X element offset: t*1048576 + rblk*16384 + slot*256 + L*4  (slot = zcol/16)
__global__ __launch_bounds__(512, 4)
void xproj_kernel(const float* __restrict__ emb,
                  const int* __restrict__ idq, const int* __restrict__ idr,
                  const int* __restrict__ lenq, const int* __restrict__ lenr,
                  const unsigned short* __restrict__ Wxp,
                  const float* __restrict__ bias,
                  unsigned short* __restrict__ X)
{
    __shared__ __align__(16) unsigned short As[64 * 264];   // 33 KB
    __shared__ int Ls2[4][64];
    __shared__ int Ids2[4][64];

    const int tid = threadIdx.x;
    const int L = tid & 63, w = tid >> 6;          // 8 waves
    const int lanelo = L & 15, lhi = L >> 4;
    const int cslice = blockIdx.y;                 // 0..3
    const int colbase = cslice * 256 + w * 32;     // wave's 32 cols
    const int slot0 = cslice * 16 + w * 2;

    // ---- Wx slice -> registers (persistent) ----
    short8 Bx[2][8];
    #pragma unroll
    for (int cf = 0; cf < 2; ++cf) {
        const unsigned short* bb = Wxp + (size_t)(colbase + cf * 16 + lanelo) * 256 + lhi * 8;
        #pragma unroll
        for (int ks = 0; ks < 8; ++ks) Bx[cf][ks] = *(const short8*)(bb + ks * 32);
    }
    // per-lane bias for the two owned cols (incl. forget bias on gate 2)
    float bc[2];
    #pragma unroll
    for (int cf = 0; cf < 2; ++cf) {
        int col = colbase + cf * 16 + lanelo;
        bc[cf] = bias[col] + ((col >= 512 && col < 768) ? 2.0f : 0.f);
    }

    // ---- stage lens/ids for this block's 4 row-tiles ----
    if (tid < 256) {
        int it = tid >> 6, rl = tid & 63;
        int rt = blockIdx.x + it * 196;
        int t = rt >> 4, r0 = (rt & 15) * 64;
        int gr = r0 + rl;
        Ls2[it][rl] = (gr < 512) ? lenq[gr] : lenr[gr - 512];
        Ids2[it][rl] = (gr < 512) ? idq[gr * TTs + t] : idr[(gr - 512) * TTs + t];
    }
    __syncthreads();

    for (int it = 0; it < 4; ++it) {
        const int rt = blockIdx.x + it * 196;
        const int t = rt >> 4;
        const int rblkb = (rt & 15) * 4;
        const int* Ls = Ls2[it];
        const int* Ids = Ids2[it];

        // ---- stage gathered emb rows -> LDS (bf16), skip dead rows ----
        float4 ev0[4], ev1[4];
        bool live[4];
        #pragma unroll
        for (int i = 0; i < 4; ++i) {
            int task = tid + i * 512;
            int rl = task >> 5, kc = (task & 31) * 8;
            live[i] = (t < Ls[rl]);
            if (live[i]) {
                const float* ep = emb + (size_t)Ids[rl] * 256 + kc;
                ev0[i] = *(const float4*)ep;
                ev1[i] = *(const float4*)(ep + 4);
            }
        }
        #pragma unroll
        for (int i = 0; i < 4; ++i) {
            if (live[i]) {
                int task = tid + i * 512;
                int rl = task >> 5, kc = (task & 31) * 8;
                short8 v;
                v[0] = (short)f2bf(ev0[i].x); v[1] = (short)f2bf(ev0[i].y);
                v[2] = (short)f2bf(ev0[i].z); v[3] = (short)f2bf(ev0[i].w);
                v[4] = (short)f2bf(ev1[i].x); v[5] = (short)f2bf(ev1[i].y);
                v[6] = (short)f2bf(ev1[i].z); v[7] = (short)f2bf(ev1[i].w);
                *(short8*)(As + rl * 264 + kc) = v;
            }
        }
        __syncthreads();

        // ---- compute: 4 row-groups x (8 ds_read + 16 MFMA) ----
        #pragma unroll
        for (int rg = 0; rg < 4; ++rg) {
            int base = rg * 16 + lhi * 4;
            int lmax = max(max(Ls[base], Ls[base + 1]), max(Ls[base + 2], Ls[base + 3]));
            bool myalive = (t < lmax);
            if (__any(myalive)) {
                f32x4 a0 = (f32x4){0.f, 0.f, 0.f, 0.f};
                f32x4 a1 = (f32x4){0.f, 0.f, 0.f, 0.f};
                const unsigned short* ar = As + (rg * 16 + lanelo) * 264 + lhi * 8;
                #pragma unroll
                for (int ks = 0; ks < 8; ++ks) {
                    short8 a = *(const short8*)(ar + ks * 32);
                    a0 = __builtin_amdgcn_mfma_f32_16x16x32_bf16(a, Bx[0][ks], a0, 0, 0, 0);
                    a1 = __builtin_amdgcn_mfma_f32_16x16x32_bf16(a, Bx[1][ks], a1, 0, 0, 0);
                }
                if (myalive) {
                    size_t off = (((size_t)(t * 64 + rblkb + rg)) * 64 + slot0) * 256 + L * 4;
                    ushort4v v0, v1;
                    #pragma unroll
                    for (int j = 0; j < 4; ++j) {
                        v0[j] = f2bf(a0[j] + bc[0]);
                        v1[j] = f2bf(a1[j] + bc[1]);
                    }
                    *(ushort4v*)(X + off) = v0;
                    *(ushort4v*)(X + off + 256) = v1;
                }
            }
        }
        __syncthreads();   // protect As/Ls before next tile's staging
    }
}

// Recurrent loop v2: 128 blocks x 8 rows, 16 waves -> 128 CUs (was 64).
// Live rows placed at tile rows {4k, 4k+1} so every lane owns exactly 2 cells
// in acc regs 0,1 -> gate VALU + transcendentals per wave HALVED, no shuffles.
// Tile rows {4k+2, 4k+3} stay zero (MFMA computes garbage there, unused).
// Wq slice register-resident (64 VGPR); h kept f32 in regs (frozen semantics);
// X read as one dword per gate, fully coalesced, one-step prefetch.
__global__ __launch_bounds__(1024, 4)
void lstm_i8_kernel(const unsigned short* __restrict__ X,
                    const signed char* __restrict__ Wq,
                    const float* __restrict__ p_i, const float* __restrict__ p_f,
                    const float* __restrict__ p_o,
                    const int* __restrict__ lenq, const int* __restrict__ lenr,
                    unsigned short* __restrict__ hfin)
{
    __shared__ int hl_i[2176];                 // 2 x 16 x 272 bytes (int8 h)
    char* hlb = (char*)hl_i;
    const int tid = threadIdx.x;
    const int L = tid & 63, w = tid >> 6;      // w 0..15
    const int blk = blockIdx.x;                // 0..127, 8 global rows each
    const int lanelo = L & 15, lhi = L >> 4;
    const int hh = w * 16 + lanelo;

    for (int i = tid; i < 2176; i += 1024) hl_i[i] = 0;

    // ---- Wh slice (int8) -> registers, persistent ----
    int4v Bw[4][4];
    #pragma unroll
    for (int g = 0; g < 4; ++g)
        #pragma unroll
        for (int kc = 0; kc < 4; ++kc)
            Bw[g][kc] = *(const int4v*)(Wq + (size_t)(g * 256 + hh) * 256 + kc * 64 + lhi * 16);

    // X addressing: global rows rA = blk*8 + lhi*2, rB = rA+1.
    // In X's 16-row tiles: rblk16 = blk>>1, tile-row tr = (blk&1)*8 + lhi*2.
    // Value (gate g, rows tr..tr+1, col hh) = dword at
    //   (g*16+w)*256 + (tr>>2)*64 + lanelo*4 + (tr&3)   [ushort elems]
    const unsigned short* xb = X + (size_t)(blk >> 1) * 16384;
    const int tr = (blk & 1) * 8 + lhi * 2;
    int xgoff[4];
    #pragma unroll
    for (int g = 0; g < 4; ++g)
        xgoff[g] = (g * 16 + w) * 256 + (tr >> 2) * 64 + lanelo * 4 + (tr & 3);

    const int ard = lanelo * 272 + lhi * 16;   // A-frag read base (bytes)

    const float pii = p_i[hh], pff = p_f[hh], poo = p_o[hh];
    const float INV = 1.f / (H_SCALE * WH_SCALE);

    int len_[2];
    #pragma unroll
    for (int c = 0; c < 2; ++c) {
        int gr = blk * 8 + lhi * 2 + c;
        len_[c] = (gr < 512) ? lenq[gr] : lenr[gr - 512];
    }

    float cst[2] = {};
    float hst[2] = {};

    // preload X for t = 0
    unsigned xr[4], xn[4];
    #pragma unroll
    for (int g = 0; g < 4; ++g) xr[g] = *(const unsigned*)(xb + xgoff[g]);

    __syncthreads();

    for (int t = 0; t < NSTEP; ++t) {
        const int rb = (t & 1) * 4352;
        const int wb = 4352 - rb;

        // unconditional clamped one-step prefetch (wave-uniform address)
        const int tn = (t + 1 < NSTEP) ? t + 1 : NSTEP - 1;
        const unsigned short* xt1 = xb + (size_t)tn * 1048576;
        #pragma unroll
        for (int g = 0; g < 4; ++g) xn[g] = *(const unsigned*)(xt1 + xgoff[g]);

        int4v acc[4];
        #pragma unroll
        for (int g = 0; g < 4; ++g) acc[g] = (int4v){0, 0, 0, 0};

        #pragma unroll
        for (int kc = 0; kc < 4; ++kc) {
            int4v a = *(const int4v*)(hlb + rb + ard + kc * 64);
            #pragma unroll
            for (int g = 0; g < 4; ++g)
                acc[g] = __builtin_amdgcn_mfma_i32_16x16x64_i8(a, Bw[g][kc], acc[g], 0, 0, 0);
        }

        #pragma unroll
        for (int c = 0; c < 2; ++c) {
            float cv = cst[c];
            float zi = fmaf((float)acc[0][c], INV, bf2f((unsigned short)(c ? (xr[0] >> 16) : (xr[0] & 0xffff))));
            float zj = fmaf((float)acc[1][c], INV, bf2f((unsigned short)(c ? (xr[1] >> 16) : (xr[1] & 0xffff))));
            float zf = fmaf((float)acc[2][c], INV, bf2f((unsigned short)(c ? (xr[2] >> 16) : (xr[2] & 0xffff))));
            float zo = fmaf((float)acc[3][c], INV, bf2f((unsigned short)(c ? (xr[3] >> 16) : (xr[3] & 0xffff))));
            float iv = sigm(fmaf(pii, cv, zi));
            float fv = sigm(fmaf(pff, cv, zf));
            float jv = ftanh(zj);
            float cn = fv * cv + iv * jv;
            float ov = sigm(fmaf(poo, cn, zo));
            float hn = ov * ftanh(cn);
            bool upd = (t < len_[c]);
            if (upd) { cst[c] = cn; hst[c] = hn; }
            // live tile row = lhi*4 + c; rows 4k+2, 4k+3 stay zero
            hlb[wb + (lhi * 4 + c) * 272 + hh] =
                (signed char)__float2int_rn(hst[c] * H_SCALE);
        }
        __syncthreads();
        #pragma unroll
        for (int g = 0; g < 4; ++g) xr[g] = xn[g];
    }

    #pragma unroll
    for (int c = 0; c < 2; ++c)
        hfin[(size_t)(blk * 8 + lhi * 2 + c) * 256 + hh] = f2bf(hst[c]);
}

#define TS 64
#define KT 16
#define LDW (TS + 4)

// qM[512x256] = bf16 h(rows 0..511) @ fp32 M[256x256]
__global__ __launch_bounds__(256)
void gemm_qM_kernel(const unsigned short* __restrict__ hA, const float* __restrict__ B,
                    float* __restrict__ C)
{
    __shared__ float As[KT][LDW];
    __shared__ float Bs[KT][LDW];
    const int tid = threadIdx.x;
    const int tx = tid & 15, ty = tid >> 4;
    const int m0 = blockIdx.x * TS, n0 = blockIdx.y * TS;
    float acc[4][4] = {};
    for (int kk = 0; kk < 256; kk += KT) {
        #pragma unroll
        for (int i = 0; i < 4; ++i) {
            int l = tid + i * 256;
            As[l & 15][l >> 4] = bf2f(hA[(m0 + (l >> 4)) * 256 + kk + (l & 15)]);
            Bs[l >> 6][l & 63] = B[(kk + (l >> 6)) * 256 + n0 + (l & 63)];
        }
        __syncthreads();
        #pragma unroll
        for (int k = 0; k < KT; ++k) {
            float4 a4 = *(const float4*)&As[k][ty * 4];
            float4 b4 = *(const float4*)&Bs[k][tx * 4];
            float av[4] = {a4.x, a4.y, a4.z, a4.w};
            float bv[4] = {b4.x, b4.y, b4.z, b4.w};
            #pragma unroll
            for (int i = 0; i < 4; ++i)
                #pragma unroll
                for (int j = 0; j < 4; ++j)
                    acc[i][j] = fmaf(av[i], bv[j], acc[i][j]);
        }
        __syncthreads();
    }
    #pragma unroll
    for (int i = 0; i < 4; ++i) {
        float4 v = {acc[i][0], acc[i][1], acc[i][2], acc[i][3]};
        *(float4*)&C[(m0 + ty * 4 + i) * 256 + n0 + tx * 4] = v;
    }
}

// D[512x512] = fp32 qM[512x256] @ (bf16 r[512x256])^T
__global__ __launch_bounds__(256)
void gemm_D_kernel(const float* __restrict__ A, const unsigned short* __restrict__ hB,
                   float* __restrict__ C)
{
    __shared__ float As[KT][LDW];
    __shared__ float Bs[KT][LDW];
    const int tid = threadIdx.x;
    const int tx = tid & 15, ty = tid >> 4;
    const int m0 = blockIdx.x * TS, n0 = blockIdx.y * TS;
    float acc[4][4] = {};
    for (int kk = 0; kk < 256; kk += KT) {
        #pragma unroll
        for (int i = 0; i < 4; ++i) {
            int l = tid + i * 256;
            As[l & 15][l >> 4] = A[(m0 + (l >> 4)) * 256 + kk + (l & 15)];
            Bs[l & 15][l >> 4] = bf2f(hB[(n0 + (l >> 4)) * 256 + kk + (l & 15)]);
        }
        __syncthreads();
        #pragma unroll
        for (int k = 0; k < KT; ++k) {
            float4 a4 = *(const float4*)&As[k][ty * 4];
            float4 b4 = *(const float4*)&Bs[k][tx * 4];
            float av[4] = {a4.x, a4.y, a4.z, a4.w};
            float bv[4] = {b4.x, b4.y, b4.z, b4.w};
            #pragma unroll
            for (int i = 0; i < 4; ++i)
                #pragma unroll
                for (int j = 0; j < 4; ++j)
                    acc[i][j] = fmaf(av[i], bv[j], acc[i][j]);
        }
        __syncthreads();
    }
    #pragma unroll
    for (int i = 0; i < 4; ++i) {
        float4 v = {acc[i][0], acc[i][1], acc[i][2], acc[i][3]};
        *(float4*)&C[(m0 + ty * 4 + i) * 512 + n0 + tx * 4] = v;
    }
}

__global__ __launch_bounds__(256)
void loss_kernel(const float* __restrict__ D, const float* __restrict__ wd,
                 float* __restrict__ out)
{
    int idx = blockIdx.x * 256 + threadIdx.x;
    int j = idx & 511;
    float d   = D[idx];
    float pos = D[j * 512 + j];
    float ww  = wd[idx];
    float wp  = wd[j * 512 + j];
    float wn  = fmaxf(0.f, ww / wp - 1.f);
    float v   = fmaxf(0.f, d - pos + wn);
    #pragma unroll
    for (int o = 32; o > 0; o >>= 1) v += __shfl_down(v, o);
    __shared__ float sm[4];
    if ((threadIdx.x & 63) == 0) sm[threadIdx.x >> 6] = v;
    __syncthreads();
    if (threadIdx.x == 0) atomicAdd(out, sm[0] + sm[1] + sm[2] + sm[3]);
}

extern "C" void kernel_launch(void* const* d_in, const int* in_sizes, int n_in,
                              void* d_out, int out_size, void* d_ws, size_t ws_size,
                              hipStream_t stream) {
    const int*   idq  = (const int*)d_in[0];
    const int*   idr  = (const int*)d_in[1];
    const int*   lenq = (const int*)d_in[2];
    const int*   lenr = (const int*)d_in[3];
    const float* wd   = (const float*)d_in[4];
    const float* emb  = (const float*)d_in[5];
    const float* W    = (const float*)d_in[6];
    const float* bias = (const float*)d_in[7];
    const float* p_i  = (const float*)d_in[8];
    const float* p_f  = (const float*)d_in[9];
    const float* p_o  = (const float*)d_in[10];
    const float* Mm   = (const float*)d_in[11];
    float* out = (float*)d_out;

    char* ws = (char*)d_ws;
    unsigned short* X    = (unsigned short*)ws;           // 49*1024*1024 bf16 = 102,760,448 B
    char* p = ws + (size_t)NSTEP * 1048576 * 2;
    unsigned short* hfin = (unsigned short*)p;  p += 1024 * 256 * 2;   // 512 KB
    unsigned short* Wxp  = (unsigned short*)p;  p += 1024 * 256 * 2;   // 512 KB
    signed char*    Wq   = (signed char*)p;     p += 1024 * 256;       // 256 KB
    float* qM = (float*)p;  p += 512 * 256 * 4;                        // 512 KB
    float* D  = (float*)p;                                             // 1 MB

    init_kernel<<<1, 64, 0, stream>>>(out);
    pack_w_kernel<<<dim3(64, 2), 256, 0, stream>>>(W, Wxp, Wq);
    xproj_kernel<<<dim3(196, 4), 512, 0, stream>>>(emb, idq, idr, lenq, lenr,
                                                   Wxp, bias, X);
    lstm_i8_kernel<<<128, 1024, 0, stream>>>(X, Wq, p_i, p_f, p_o,
                                             lenq, lenr, hfin);
    gemm_qM_kernel<<<dim3(8, 4), 256, 0, stream>>>(hfin, Mm, qM);
    gemm_D_kernel<<<dim3(8, 8), 256, 0, stream>>>(qM, hfin + 512 * 256, D);
    loss_kernel<<<1024, 256, 0, stream>>>(D, wd, out);
}

// Round 9
// 161.209 us; speedup vs baseline: 3.3109x; 1.2709x over previous
//
#include <hip/hip_runtime.h>

#define TTs 50
#define NSTEP 49

using short8   = __attribute__((ext_vector_type(8))) short;
using ushort4v = __attribute__((ext_vector_type(4))) unsigned short;
using f32x4    = __attribute__((ext_vector_type(4))) float;
using int4v    = __attribute__((ext_vector_type(4))) int;

__device__ __forceinline__ unsigned short f2bf(float f) {
    unsigned u = __builtin_bit_cast(unsigned, f);
    u += 0x7FFFu + ((u >> 16) & 1u);          // RNE
    return (unsigned short)(u >> 16);
}
__device__ __forceinline__ float bf2f(unsigned short s) {
    unsigned u = ((unsigned)s) << 16;
    return __builtin_bit_cast(float, u);
}
__device__ __forceinline__ float frcp(float x) { return __builtin_amdgcn_rcpf(x); }
// rcp-based: exp overflow -> inf -> rcp -> 0 (correct saturation)
__device__ __forceinline__ float sigm(float x)  { return frcp(1.f + __expf(-x)); }
__device__ __forceinline__ float ftanh(float x) { return 1.f - 2.f * frcp(__expf(2.f * x) + 1.f); }

#define WH_SCALE 512.f
#define H_SCALE  127.f

__global__ __launch_bounds__(64)
void init_kernel(float* __restrict__ out) { if (threadIdx.x == 0) out[0] = 0.f; }

// Pack W (f32 [512][1024]):
//  y=0: Wx rows 0..255   -> Wxp bf16 [c][k] col-major frag layout
//  y=1: Wh rows 256..511 -> Wq  int8 [c][k] col-major, scaled by 512
__global__ __launch_bounds__(256)
void pack_w_kernel(const float* __restrict__ W,
                   unsigned short* __restrict__ Wxp, signed char* __restrict__ Wq)
{
    __shared__ float ld[64][65];
    const int koff = blockIdx.y * 256;
    const int k0 = (blockIdx.x & 3) * 64, c0 = (blockIdx.x >> 2) * 64;
    const int tid = threadIdx.x;
    #pragma unroll
    for (int i = 0; i < 16; ++i) {
        int idx = tid + i * 256;
        ld[idx >> 6][idx & 63] = W[(size_t)(koff + k0 + (idx >> 6)) * 1024 + c0 + (idx & 63)];
    }
    __syncthreads();
    if (blockIdx.y == 0) {
        #pragma unroll
        for (int j = 0; j < 2; ++j) {
            int idx = tid + j * 256;
            int cl = idx >> 3, kc = (idx & 7) * 8;
            short8 v;
            #pragma unroll
            for (int e = 0; e < 8; ++e) v[e] = (short)f2bf(ld[kc + e][cl]);
            *(short8*)(Wxp + (size_t)(c0 + cl) * 256 + k0 + kc) = v;
        }
    } else {
        #pragma unroll
        for (int j = 0; j < 2; ++j) {
            int idx = tid + j * 256;
            int cl = idx >> 3, kc = (idx & 7) * 8;
            unsigned long long u = 0;
            #pragma unroll
            for (int e = 0; e < 8; ++e) {
                float v = ld[kc + e][cl] * WH_SCALE;
                int q = __float2int_rn(fminf(fmaxf(v, -127.f), 127.f));
                u |= (unsigned long long)(unsigned char)(signed char)q << (8 * e);
            }
            *(unsigned long long*)(Wq + (size_t)(c0 + cl) * 256 + k0 + kc) = u;
        }
    }
}

// X projection v4 (unchanged): Wx register-resident; block = 512 thr owns a
// 256-col slice (blockIdx.y of 4); sweeps 4 row-tiles. Bias folded into X.
// X element offset: t*1048576 + rblk*16384 + slot*256 + L*4  (slot = zcol/16)
__global__ __launch_bounds__(512, 4)
void xproj_kernel(const float* __restrict__ emb,
                  const int* __restrict__ idq, const int* __restrict__ idr,
                  const int* __restrict__ lenq, const int* __restrict__ lenr,
                  const unsigned short* __restrict__ Wxp,
                  const float* __restrict__ bias,
                  unsigned short* __restrict__ X)
{
    __shared__ __align__(16) unsigned short As[64 * 264];   // 33 KB
    __shared__ int Ls2[4][64];
    __shared__ int Ids2[4][64];

    const int tid = threadIdx.x;
    const int L = tid & 63, w = tid >> 6;          // 8 waves
    const int lanelo = L & 15, lhi = L >> 4;
    const int cslice = blockIdx.y;                 // 0..3
    const int colbase = cslice * 256 + w * 32;     // wave's 32 cols
    const int slot0 = cslice * 16 + w * 2;

    // ---- Wx slice -> registers (persistent) ----
    short8 Bx[2][8];
    #pragma unroll
    for (int cf = 0; cf < 2; ++cf) {
        const unsigned short* bb = Wxp + (size_t)(colbase + cf * 16 + lanelo) * 256 + lhi * 8;
        #pragma unroll
        for (int ks = 0; ks < 8; ++ks) Bx[cf][ks] = *(const short8*)(bb + ks * 32);
    }
    // per-lane bias for the two owned cols (incl. forget bias on gate 2)
    float bc[2];
    #pragma unroll
    for (int cf = 0; cf < 2; ++cf) {
        int col = colbase + cf * 16 + lanelo;
        bc[cf] = bias[col] + ((col >= 512 && col < 768) ? 2.0f : 0.f);
    }

    // ---- stage lens/ids for this block's 4 row-tiles ----
    if (tid < 256) {
        int it = tid >> 6, rl = tid & 63;
        int rt = blockIdx.x + it * 196;
        int t = rt >> 4, r0 = (rt & 15) * 64;
        int gr = r0 + rl;
        Ls2[it][rl] = (gr < 512) ? lenq[gr] : lenr[gr - 512];
        Ids2[it][rl] = (gr < 512) ? idq[gr * TTs + t] : idr[(gr - 512) * TTs + t];
    }
    __syncthreads();

    for (int it = 0; it < 4; ++it) {
        const int rt = blockIdx.x + it * 196;
        const int t = rt >> 4;
        const int rblkb = (rt & 15) * 4;
        const int* Ls = Ls2[it];
        const int* Ids = Ids2[it];

        // ---- stage gathered emb rows -> LDS (bf16), skip dead rows ----
        float4 ev0[4], ev1[4];
        bool live[4];
        #pragma unroll
        for (int i = 0; i < 4; ++i) {
            int task = tid + i * 512;
            int rl = task >> 5, kc = (task & 31) * 8;
            live[i] = (t < Ls[rl]);
            if (live[i]) {
                const float* ep = emb + (size_t)Ids[rl] * 256 + kc;
                ev0[i] = *(const float4*)ep;
                ev1[i] = *(const float4*)(ep + 4);
            }
        }
        #pragma unroll
        for (int i = 0; i < 4; ++i) {
            if (live[i]) {
                int task = tid + i * 512;
                int rl = task >> 5, kc = (task & 31) * 8;
                short8 v;
                v[0] = (short)f2bf(ev0[i].x); v[1] = (short)f2bf(ev0[i].y);
                v[2] = (short)f2bf(ev0[i].z); v[3] = (short)f2bf(ev0[i].w);
                v[4] = (short)f2bf(ev1[i].x); v[5] = (short)f2bf(ev1[i].y);
                v[6] = (short)f2bf(ev1[i].z); v[7] = (short)f2bf(ev1[i].w);
                *(short8*)(As + rl * 264 + kc) = v;
            }
        }
        __syncthreads();

        // ---- compute: 4 row-groups x (8 ds_read + 16 MFMA) ----
        #pragma unroll
        for (int rg = 0; rg < 4; ++rg) {
            int base = rg * 16 + lhi * 4;
            int lmax = max(max(Ls[base], Ls[base + 1]), max(Ls[base + 2], Ls[base + 3]));
            bool myalive = (t < lmax);
            if (__any(myalive)) {
                f32x4 a0 = (f32x4){0.f, 0.f, 0.f, 0.f};
                f32x4 a1 = (f32x4){0.f, 0.f, 0.f, 0.f};
                const unsigned short* ar = As + (rg * 16 + lanelo) * 264 + lhi * 8;
                #pragma unroll
                for (int ks = 0; ks < 8; ++ks) {
                    short8 a = *(const short8*)(ar + ks * 32);
                    a0 = __builtin_amdgcn_mfma_f32_16x16x32_bf16(a, Bx[0][ks], a0, 0, 0, 0);
                    a1 = __builtin_amdgcn_mfma_f32_16x16x32_bf16(a, Bx[1][ks], a1, 0, 0, 0);
                }
                if (myalive) {
                    size_t off = (((size_t)(t * 64 + rblkb + rg)) * 64 + slot0) * 256 + L * 4;
                    ushort4v v0, v1;
                    #pragma unroll
                    for (int j = 0; j < 4; ++j) {
                        v0[j] = f2bf(a0[j] + bc[0]);
                        v1[j] = f2bf(a1[j] + bc[1]);
                    }
                    *(ushort4v*)(X + off) = v0;
                    *(ushort4v*)(X + off + 256) = v1;
                }
            }
        }
        __syncthreads();   // protect As/Ls before next tile's staging
    }
}

// Recurrent loop v3: 256 blocks x 4 rows, 16 waves -> ALL 256 CUs.
// Live rows at tile rows {4k} (k=lhi) -> every lane owns exactly 1 cell in
// acc reg 0: gate VALU/transcendentals per wave halved vs v2, no shuffles.
// All divisions replaced with v_rcp (IEEE div was ~10 VALU ops each).
// X read: 1 ushort/lane/gate = contiguous 128 B per (g,w) region, coalesced.
__global__ __launch_bounds__(1024, 4)
void lstm_i8_kernel(const unsigned short* __restrict__ X,
                    const signed char* __restrict__ Wq,
                    const float* __restrict__ p_i, const float* __restrict__ p_f,
                    const float* __restrict__ p_o,
                    const int* __restrict__ lenq, const int* __restrict__ lenr,
                    unsigned short* __restrict__ hfin)
{
    __shared__ int hl_i[2176];                 // 2 x 16 x 272 bytes (int8 h)
    char* hlb = (char*)hl_i;
    const int tid = threadIdx.x;
    const int L = tid & 63, w = tid >> 6;      // w 0..15
    const int blk = blockIdx.x;                // 0..255, 4 global rows each
    const int lanelo = L & 15, lhi = L >> 4;
    const int hh = w * 16 + lanelo;

    for (int i = tid; i < 2176; i += 1024) hl_i[i] = 0;

    // ---- Wh slice (int8) -> registers, persistent ----
    int4v Bw[4][4];
    #pragma unroll
    for (int g = 0; g < 4; ++g)
        #pragma unroll
        for (int kc = 0; kc < 4; ++kc)
            Bw[g][kc] = *(const int4v*)(Wq + (size_t)(g * 256 + hh) * 256 + kc * 64 + lhi * 16);

    // X addressing: global row gr = blk*4 + lhi; X-tile rblk16 = blk>>2,
    // tile row tr = (blk&3)*4 + lhi  =>  tr>>2 = blk&3 (uniform), tr&3 = lhi.
    // ushort element offset: (g*16+w)*256 + (blk&3)*64 + lanelo*4 + lhi
    const unsigned short* xb = X + (size_t)(blk >> 2) * 16384;
    int xgoff[4];
    #pragma unroll
    for (int g = 0; g < 4; ++g)
        xgoff[g] = (g * 16 + w) * 256 + (blk & 3) * 64 + lanelo * 4 + lhi;

    const int ard = lanelo * 272 + lhi * 16;   // A-frag read base (bytes)
    const int awr = (lhi * 4) * 272 + hh;      // live local row = lhi*4

    const float pii = p_i[hh], pff = p_f[hh], poo = p_o[hh];
    const float INV = 1.f / (H_SCALE * WH_SCALE);

    const int gr = blk * 4 + lhi;
    const int len_ = (gr < 512) ? lenq[gr] : lenr[gr - 512];

    float cst = 0.f;
    float hst = 0.f;

    // preload X for t = 0
    unsigned short xr[4], xn[4];
    #pragma unroll
    for (int g = 0; g < 4; ++g) xr[g] = xb[xgoff[g]];

    __syncthreads();

    for (int t = 0; t < NSTEP; ++t) {
        const int rb = (t & 1) * 4352;
        const int wb = 4352 - rb;

        // clamped one-step prefetch (wave-uniform address, no divergence)
        const int tn = (t + 1 < NSTEP) ? t + 1 : NSTEP - 1;
        const unsigned short* xt1 = xb + (size_t)tn * 1048576;
        #pragma unroll
        for (int g = 0; g < 4; ++g) xn[g] = xt1[xgoff[g]];

        int4v acc[4];
        #pragma unroll
        for (int g = 0; g < 4; ++g) acc[g] = (int4v){0, 0, 0, 0};

        #pragma unroll
        for (int kc = 0; kc < 4; ++kc) {
            int4v a = *(const int4v*)(hlb + rb + ard + kc * 64);
            #pragma unroll
            for (int g = 0; g < 4; ++g)
                acc[g] = __builtin_amdgcn_mfma_i32_16x16x64_i8(a, Bw[g][kc], acc[g], 0, 0, 0);
        }

        {
            float cv = cst;
            float zi = fmaf((float)acc[0][0], INV, bf2f(xr[0]));
            float zj = fmaf((float)acc[1][0], INV, bf2f(xr[1]));
            float zf = fmaf((float)acc[2][0], INV, bf2f(xr[2]));
            float zo = fmaf((float)acc[3][0], INV, bf2f(xr[3]));
            float iv = sigm(fmaf(pii, cv, zi));
            float fv = sigm(fmaf(pff, cv, zf));
            float jv = ftanh(zj);
            float cn = fv * cv + iv * jv;
            float ov = sigm(fmaf(poo, cn, zo));
            float hn = ov * ftanh(cn);
            bool upd = (t < len_);
            if (upd) { cst = cn; hst = hn; }
            // live local row = lhi*4; rows 4k+1..4k+3 stay zero
            hlb[wb + awr] = (signed char)__float2int_rn(hst * H_SCALE);
        }
        __syncthreads();
        #pragma unroll
        for (int g = 0; g < 4; ++g) xr[g] = xn[g];
    }

    hfin[(size_t)gr * 256 + hh] = f2bf(hst);
}

#define TS 64
#define KT 16
#define LDW (TS + 4)

// qM[512x256] = bf16 h(rows 0..511) @ fp32 M[256x256]
__global__ __launch_bounds__(256)
void gemm_qM_kernel(const unsigned short* __restrict__ hA, const float* __restrict__ B,
                    float* __restrict__ C)
{
    __shared__ float As[KT][LDW];
    __shared__ float Bs[KT][LDW];
    const int tid = threadIdx.x;
    const int tx = tid & 15, ty = tid >> 4;
    const int m0 = blockIdx.x * TS, n0 = blockIdx.y * TS;
    float acc[4][4] = {};
    for (int kk = 0; kk < 256; kk += KT) {
        #pragma unroll
        for (int i = 0; i < 4; ++i) {
            int l = tid + i * 256;
            As[l & 15][l >> 4] = bf2f(hA[(m0 + (l >> 4)) * 256 + kk + (l & 15)]);
            Bs[l >> 6][l & 63] = B[(kk + (l >> 6)) * 256 + n0 + (l & 63)];
        }
        __syncthreads();
        #pragma unroll
        for (int k = 0; k < KT; ++k) {
            float4 a4 = *(const float4*)&As[k][ty * 4];
            float4 b4 = *(const float4*)&Bs[k][tx * 4];
            float av[4] = {a4.x, a4.y, a4.z, a4.w};
            float bv[4] = {b4.x, b4.y, b4.z, b4.w};
            #pragma unroll
            for (int i = 0; i < 4; ++i)
                #pragma unroll
                for (int j = 0; j < 4; ++j)
                    acc[i][j] = fmaf(av[i], bv[j], acc[i][j]);
        }
        __syncthreads();
    }
    #pragma unroll
    for (int i = 0; i < 4; ++i) {
        float4 v = {acc[i][0], acc[i][1], acc[i][2], acc[i][3]};
        *(float4*)&C[(m0 + ty * 4 + i) * 256 + n0 + tx * 4] = v;
    }
}

// D[512x512] = fp32 qM[512x256] @ (bf16 r[512x256])^T
__global__ __launch_bounds__(256)
void gemm_D_kernel(const float* __restrict__ A, const unsigned short* __restrict__ hB,
                   float* __restrict__ C)
{
    __shared__ float As[KT][LDW];
    __shared__ float Bs[KT][LDW];
    const int tid = threadIdx.x;
    const int tx = tid & 15, ty = tid >> 4;
    const int m0 = blockIdx.x * TS, n0 = blockIdx.y * TS;
    float acc[4][4] = {};
    for (int kk = 0; kk < 256; kk += KT) {
        #pragma unroll
        for (int i = 0; i < 4; ++i) {
            int l = tid + i * 256;
            As[l & 15][l >> 4] = A[(m0 + (l >> 4)) * 256 + kk + (l & 15)];
            Bs[l & 15][l >> 4] = bf2f(hB[(n0 + (l >> 4)) * 256 + kk + (l & 15)]);
        }
        __syncthreads();
        #pragma unroll
        for (int k = 0; k < KT; ++k) {
            float4 a4 = *(const float4*)&As[k][ty * 4];
            float4 b4 = *(const float4*)&Bs[k][tx * 4];
            float av[4] = {a4.x, a4.y, a4.z, a4.w};
            float bv[4] = {b4.x, b4.y, b4.z, b4.w};
            #pragma unroll
            for (int i = 0; i < 4; ++i)
                #pragma unroll
                for (int j = 0; j < 4; ++j)
                    acc[i][j] = fmaf(av[i], bv[j], acc[i][j]);
        }
        __syncthreads();
    }
    #pragma unroll
    for (int i = 0; i < 4; ++i) {
        float4 v = {acc[i][0], acc[i][1], acc[i][2], acc[i][3]};
        *(float4*)&C[(m0 + ty * 4 + i) * 512 + n0 + tx * 4] = v;
    }
}

__global__ __launch_bounds__(256)
void loss_kernel(const float* __restrict__ D, const float* __restrict__ wd,
                 float* __restrict__ out)
{
    int idx = blockIdx.x * 256 + threadIdx.x;
    int j = idx & 511;
    float d   = D[idx];
    float pos = D[j * 512 + j];
    float ww  = wd[idx];
    float wp  = wd[j * 512 + j];
    float wn  = fmaxf(0.f, fmaf(ww, frcp(wp), -1.f));
    float v   = fmaxf(0.f, d - pos + wn);
    #pragma unroll
    for (int o = 32; o > 0; o >>= 1) v += __shfl_down(v, o);
    __shared__ float sm[4];
    if ((threadIdx.x & 63) == 0) sm[threadIdx.x >> 6] = v;
    __syncthreads();
    if (threadIdx.x == 0) atomicAdd(out, sm[0] + sm[1] + sm[2] + sm[3]);
}

extern "C" void kernel_launch(void* const* d_in, const int* in_sizes, int n_in,
                              void* d_out, int out_size, void* d_ws, size_t ws_size,
                              hipStream_t stream) {
    const int*   idq  = (const int*)d_in[0];
    const int*   idr  = (const int*)d_in[1];
    const int*   lenq = (const int*)d_in[2];
    const int*   lenr = (const int*)d_in[3];
    const float* wd   = (const float*)d_in[4];
    const float* emb  = (const float*)d_in[5];
    const float* W    = (const float*)d_in[6];
    const float* bias = (const float*)d_in[7];
    const float* p_i  = (const float*)d_in[8];
    const float* p_f  = (const float*)d_in[9];
    const float* p_o  = (const float*)d_in[10];
    const float* Mm   = (const float*)d_in[11];
    float* out = (float*)d_out;

    char* ws = (char*)d_ws;
    unsigned short* X    = (unsigned short*)ws;           // 49*1024*1024 bf16 = 102,760,448 B
    char* p = ws + (size_t)NSTEP * 1048576 * 2;
    unsigned short* hfin = (unsigned short*)p;  p += 1024 * 256 * 2;   // 512 KB
    unsigned short* Wxp  = (unsigned short*)p;  p += 1024 * 256 * 2;   // 512 KB
    signed char*    Wq   = (signed char*)p;     p += 1024 * 256;       // 256 KB
    float* qM = (float*)p;  p += 512 * 256 * 4;                        // 512 KB
    float* D  = (float*)p;                                             // 1 MB

    init_kernel<<<1, 64, 0, stream>>>(out);
    pack_w_kernel<<<dim3(64, 2), 256, 0, stream>>>(W, Wxp, Wq);
    xproj_kernel<<<dim3(196, 4), 512, 0, stream>>>(emb, idq, idr, lenq, lenr,
                                                   Wxp, bias, X);
    lstm_i8_kernel<<<256, 1024, 0, stream>>>(X, Wq, p_i, p_f, p_o,
                                             lenq, lenr, hfin);
    gemm_qM_kernel<<<dim3(8, 4), 256, 0, stream>>>(hfin, Mm, qM);
    gemm_D_kernel<<<dim3(8, 8), 256, 0, stream>>>(qM, hfin + 512 * 256, D);
    loss_kernel<<<1024, 256, 0, stream>>>(D, wd, out);
}

// Round 10
// 150.052 us; speedup vs baseline: 3.5570x; 1.0744x over previous
//
#include <hip/hip_runtime.h>

#define TTs 50
#define NSTEP 49

using short8   = __attribute__((ext_vector_type(8))) short;
using ushort4v = __attribute__((ext_vector_type(4))) unsigned short;
using f32x4    = __attribute__((ext_vector_type(4))) float;
using int4v    = __attribute__((ext_vector_type(4))) int;

__device__ __forceinline__ unsigned short f2bf(float f) {
    unsigned u = __builtin_bit_cast(unsigned, f);
    u += 0x7FFFu + ((u >> 16) & 1u);          // RNE
    return (unsigned short)(u >> 16);
}
__device__ __forceinline__ float bf2f(unsigned short s) {
    unsigned u = ((unsigned)s) << 16;
    return __builtin_bit_cast(float, u);
}
__device__ __forceinline__ float frcp(float x) { return __builtin_amdgcn_rcpf(x); }
// rcp-based: exp overflow -> inf -> rcp -> 0 (correct saturation)
__device__ __forceinline__ float sigm(float x)  { return frcp(1.f + __expf(-x)); }
__device__ __forceinline__ float ftanh(float x) { return 1.f - 2.f * frcp(__expf(2.f * x) + 1.f); }

#define WH_SCALE 512.f
#define H_SCALE  127.f

// Counting sort of the 1024 rows by length, DESCENDING. perm[rank] = orig row.
// Tie order is atomic-dependent but the final loss is invariant (per-row math
// is independent of tile co-residents; hfin is written at the original index).
__global__ __launch_bounds__(1024)
void sort_kernel(const int* __restrict__ lenq, const int* __restrict__ lenr,
                 int* __restrict__ perm, float* __restrict__ out)
{
    __shared__ int cnt[64];
    const int tid = threadIdx.x;
    if (tid == 0) out[0] = 0.f;
    if (tid < 64) cnt[tid] = 0;
    __syncthreads();
    const int l = (tid < 512) ? lenq[tid] : lenr[tid - 512];   // 1..49
    atomicAdd(&cnt[l], 1);
    __syncthreads();
    if (tid == 0) {
        int acc = 0;
        for (int v = 49; v >= 1; --v) { int c = cnt[v]; cnt[v] = acc; acc += c; }
    }
    __syncthreads();
    const int rank = atomicAdd(&cnt[l], 1);
    perm[rank] = tid;
}

// Pack W (f32 [512][1024]):
//  y=0: Wx rows 0..255   -> Wxp bf16 [c][k] col-major frag layout
//  y=1: Wh rows 256..511 -> Wq  int8 [c][k] col-major, scaled by 512
__global__ __launch_bounds__(256)
void pack_w_kernel(const float* __restrict__ W,
                   unsigned short* __restrict__ Wxp, signed char* __restrict__ Wq)
{
    __shared__ float ld[64][65];
    const int koff = blockIdx.y * 256;
    const int k0 = (blockIdx.x & 3) * 64, c0 = (blockIdx.x >> 2) * 64;
    const int tid = threadIdx.x;
    #pragma unroll
    for (int i = 0; i < 16; ++i) {
        int idx = tid + i * 256;
        ld[idx >> 6][idx & 63] = W[(size_t)(koff + k0 + (idx >> 6)) * 1024 + c0 + (idx & 63)];
    }
    __syncthreads();
    if (blockIdx.y == 0) {
        #pragma unroll
        for (int j = 0; j < 2; ++j) {
            int idx = tid + j * 256;
            int cl = idx >> 3, kc = (idx & 7) * 8;
            short8 v;
            #pragma unroll
            for (int e = 0; e < 8; ++e) v[e] = (short)f2bf(ld[kc + e][cl]);
            *(short8*)(Wxp + (size_t)(c0 + cl) * 256 + k0 + kc) = v;
        }
    } else {
        #pragma unroll
        for (int j = 0; j < 2; ++j) {
            int idx = tid + j * 256;
            int cl = idx >> 3, kc = (idx & 7) * 8;
            unsigned long long u = 0;
            #pragma unroll
            for (int e = 0; e < 8; ++e) {
                float v = ld[kc + e][cl] * WH_SCALE;
                int q = __float2int_rn(fminf(fmaxf(v, -127.f), 127.f));
                u |= (unsigned long long)(unsigned char)(signed char)q << (8 * e);
            }
            *(unsigned long long*)(Wq + (size_t)(c0 + cl) * 256 + k0 + kc) = u;
        }
    }
}

// X projection v5: rows processed in SORTED order (perm). Per-it whole-tile
// skip when t >= max length in the tile (sorted desc -> first row is max).
// Wx register-resident; block = 512 thr owns a 256-col slice (y of 4),
// sweeps 4 row-tiles. Bias (+FORGET_BIAS) folded into the stored X.
// X element offset: t*1048576 + rblk*16384 + slot*256 + L*4  (slot = zcol/16)
__global__ __launch_bounds__(512, 4)
void xproj_kernel(const float* __restrict__ emb,
                  const int* __restrict__ idq, const int* __restrict__ idr,
                  const int* __restrict__ lenq, const int* __restrict__ lenr,
                  const int* __restrict__ perm,
                  const unsigned short* __restrict__ Wxp,
                  const float* __restrict__ bias,
                  unsigned short* __restrict__ X)
{
    __shared__ __align__(16) unsigned short As[64 * 264];   // 33 KB
    __shared__ int Ls2[4][64];
    __shared__ int Ids2[4][64];
    __shared__ int Tmax[4];

    const int tid = threadIdx.x;
    const int L = tid & 63, w = tid >> 6;          // 8 waves
    const int lanelo = L & 15, lhi = L >> 4;
    const int cslice = blockIdx.y;                 // 0..3
    const int colbase = cslice * 256 + w * 32;     // wave's 32 cols
    const int slot0 = cslice * 16 + w * 2;

    // ---- Wx slice -> registers (persistent) ----
    short8 Bx[2][8];
    #pragma unroll
    for (int cf = 0; cf < 2; ++cf) {
        const unsigned short* bb = Wxp + (size_t)(colbase + cf * 16 + lanelo) * 256 + lhi * 8;
        #pragma unroll
        for (int ks = 0; ks < 8; ++ks) Bx[cf][ks] = *(const short8*)(bb + ks * 32);
    }
    // per-lane bias for the two owned cols (incl. forget bias on gate 2)
    float bc[2];
    #pragma unroll
    for (int cf = 0; cf < 2; ++cf) {
        int col = colbase + cf * 16 + lanelo;
        bc[cf] = bias[col] + ((col >= 512 && col < 768) ? 2.0f : 0.f);
    }

    // ---- stage lens/ids (sorted order) for this block's 4 row-tiles ----
    if (tid < 256) {
        int it = tid >> 6, rl = tid & 63;
        int rt = blockIdx.x + it * 196;
        int t = rt >> 4, r0 = (rt & 15) * 64;
        int gr = perm[r0 + rl];
        int len = (gr < 512) ? lenq[gr] : lenr[gr - 512];
        Ls2[it][rl] = len;
        Ids2[it][rl] = (gr < 512) ? idq[gr * TTs + t] : idr[(gr - 512) * TTs + t];
        if (rl == 0) Tmax[it] = len;               // sorted desc -> max of tile
    }
    __syncthreads();

    for (int it = 0; it < 4; ++it) {
        const int rt = blockIdx.x + it * 196;
        const int t = rt >> 4;
        const int rblkb = (rt & 15) * 4;
        if (t >= Tmax[it]) continue;               // whole tile dead (uniform)
        const int* Ls = Ls2[it];
        const int* Ids = Ids2[it];

        // ---- stage gathered emb rows -> LDS (bf16), skip dead rows ----
        float4 ev0[4], ev1[4];
        bool live[4];
        #pragma unroll
        for (int i = 0; i < 4; ++i) {
            int task = tid + i * 512;
            int rl = task >> 5, kc = (task & 31) * 8;
            live[i] = (t < Ls[rl]);
            if (live[i]) {
                const float* ep = emb + (size_t)Ids[rl] * 256 + kc;
                ev0[i] = *(const float4*)ep;
                ev1[i] = *(const float4*)(ep + 4);
            }
        }
        #pragma unroll
        for (int i = 0; i < 4; ++i) {
            if (live[i]) {
                int task = tid + i * 512;
                int rl = task >> 5, kc = (task & 31) * 8;
                short8 v;
                v[0] = (short)f2bf(ev0[i].x); v[1] = (short)f2bf(ev0[i].y);
                v[2] = (short)f2bf(ev0[i].z); v[3] = (short)f2bf(ev0[i].w);
                v[4] = (short)f2bf(ev1[i].x); v[5] = (short)f2bf(ev1[i].y);
                v[6] = (short)f2bf(ev1[i].z); v[7] = (short)f2bf(ev1[i].w);
                *(short8*)(As + rl * 264 + kc) = v;
            }
        }
        __syncthreads();

        // ---- compute: 4 row-groups x (8 ds_read + 16 MFMA) ----
        #pragma unroll
        for (int rg = 0; rg < 4; ++rg) {
            int base = rg * 16 + lhi * 4;
            int lmax = max(max(Ls[base], Ls[base + 1]), max(Ls[base + 2], Ls[base + 3]));
            bool myalive = (t < lmax);
            if (__any(myalive)) {
                f32x4 a0 = (f32x4){0.f, 0.f, 0.f, 0.f};
                f32x4 a1 = (f32x4){0.f, 0.f, 0.f, 0.f};
                const unsigned short* ar = As + (rg * 16 + lanelo) * 264 + lhi * 8;
                #pragma unroll
                for (int ks = 0; ks < 8; ++ks) {
                    short8 a = *(const short8*)(ar + ks * 32);
                    a0 = __builtin_amdgcn_mfma_f32_16x16x32_bf16(a, Bx[0][ks], a0, 0, 0, 0);
                    a1 = __builtin_amdgcn_mfma_f32_16x16x32_bf16(a, Bx[1][ks], a1, 0, 0, 0);
                }
                if (myalive) {
                    size_t off = (((size_t)(t * 64 + rblkb + rg)) * 64 + slot0) * 256 + L * 4;
                    ushort4v v0, v1;
                    #pragma unroll
                    for (int j = 0; j < 4; ++j) {
                        v0[j] = f2bf(a0[j] + bc[0]);
                        v1[j] = f2bf(a1[j] + bc[1]);
                    }
                    *(ushort4v*)(X + off) = v0;
                    *(ushort4v*)(X + off + 256) = v1;
                }
            }
        }
        __syncthreads();   // protect As/Ls before next tile's staging
    }
}

// Recurrent loop v4: 256 blocks x 4 SORTED rows, 16 waves, all 256 CUs.
// - h LDS shrunk to 4 live rows (stride 288 B -> dword-bank 8r+4lhi, distinct;
//   b128 reads at most 2-way = free). Only lanes lanelo%4==0 issue the A-read;
//   other lanes keep a[]=0 (hoisted out of the loop) -> LDS read traffic /4.
// - X pointer advanced by a scalar += 1MB per step (no per-step 64b mul);
//   last-iteration prefetch redirected to xb (uniform cselect, value unused).
// - Loop bound = block's max length (sorted desc -> first row of block).
__global__ __launch_bounds__(1024, 4)
void lstm_i8_kernel(const unsigned short* __restrict__ X,
                    const signed char* __restrict__ Wq,
                    const float* __restrict__ p_i, const float* __restrict__ p_f,
                    const float* __restrict__ p_o,
                    const int* __restrict__ lenq, const int* __restrict__ lenr,
                    const int* __restrict__ perm,
                    unsigned short* __restrict__ hfin)
{
    __shared__ __align__(16) char hl[2 * 4 * 288];   // 2304 B, dbuf x 4 rows
    const int tid = threadIdx.x;
    const int L = tid & 63, w = tid >> 6;      // w 0..15
    const int blk = blockIdx.x;                // 4 sorted rows each
    const int lanelo = L & 15, lhi = L >> 4;
    const int hh = w * 16 + lanelo;

    if (tid < 576) ((int*)hl)[tid] = 0;

    // ---- Wh slice (int8) -> registers, persistent ----
    int4v Bw[4][4];
    #pragma unroll
    for (int g = 0; g < 4; ++g)
        #pragma unroll
        for (int kc = 0; kc < 4; ++kc)
            Bw[g][kc] = *(const int4v*)(Wq + (size_t)(g * 256 + hh) * 256 + kc * 64 + lhi * 16);

    // X addressing (sorted positions): tile rblk16 = blk>>2, tr = (blk&3)*4+lhi
    // ushort element offset: (g*16+w)*256 + (blk&3)*64 + lanelo*4 + lhi
    const unsigned short* xb = X + (size_t)(blk >> 2) * 16384;
    int xgoff[4];
    #pragma unroll
    for (int g = 0; g < 4; ++g)
        xgoff[g] = (g * 16 + w) * 256 + (blk & 3) * 64 + lanelo * 4 + lhi;

    const bool rdlane = (lanelo & 3) == 0;     // 16 lanes read; rest hold zeros
    const int ard = (lanelo >> 2) * 288 + lhi * 16;  // live row = lanelo>>2
    const int awr = lhi * 288 + hh;                   // live row = lhi

    const float pii = p_i[hh], pff = p_f[hh], poo = p_o[hh];
    const float INV = 1.f / (H_SCALE * WH_SCALE);

    const int gr = perm[blk * 4 + lhi];
    const int len_ = (gr < 512) ? lenq[gr] : lenr[gr - 512];
    const int p0 = perm[blk * 4];
    const int blkmax = (p0 < 512) ? lenq[p0] : lenr[p0 - 512];  // uniform

    float cst = 0.f;
    float hst = 0.f;

    // A-fragments: rows != 4k are permanently zero (init hoisted out of loop)
    int4v a[4];
    #pragma unroll
    for (int kc = 0; kc < 4; ++kc) a[kc] = (int4v){0, 0, 0, 0};

    // preload X for t = 0 (always written: len >= 1)
    unsigned short xr[4], xn[4];
    #pragma unroll
    for (int g = 0; g < 4; ++g) xr[g] = xb[xgoff[g]];
    const unsigned short* xp = xb + 1048576;   // scalar, advances 1 MB/step

    __syncthreads();

    for (int t = 0; t < blkmax; ++t) {
        const int rb = (t & 1) * 1152;
        const int wb = 1152 - rb;

        // prefetch next step (uniform cselect keeps the last read in-bounds)
        const unsigned short* xs = (t + 1 < blkmax) ? xp : xb;
        #pragma unroll
        for (int g = 0; g < 4; ++g) xn[g] = xs[xgoff[g]];
        xp += 1048576;

        if (rdlane) {
            #pragma unroll
            for (int kc = 0; kc < 4; ++kc)
                a[kc] = *(const int4v*)(hl + rb + ard + kc * 64);
        }

        int4v acc[4];
        #pragma unroll
        for (int g = 0; g < 4; ++g) acc[g] = (int4v){0, 0, 0, 0};
        #pragma unroll
        for (int kc = 0; kc < 4; ++kc)
            #pragma unroll
            for (int g = 0; g < 4; ++g)
                acc[g] = __builtin_amdgcn_mfma_i32_16x16x64_i8(a[kc], Bw[g][kc], acc[g], 0, 0, 0);

        {
            float cv = cst;
            float zi = fmaf((float)acc[0][0], INV, bf2f(xr[0]));
            float zj = fmaf((float)acc[1][0], INV, bf2f(xr[1]));
            float zf = fmaf((float)acc[2][0], INV, bf2f(xr[2]));
            float zo = fmaf((float)acc[3][0], INV, bf2f(xr[3]));
            float iv = sigm(fmaf(pii, cv, zi));
            float fv = sigm(fmaf(pff, cv, zf));
            float jv = ftanh(zj);
            float cn = fv * cv + iv * jv;
            float ov = sigm(fmaf(poo, cn, zo));
            float hn = ov * ftanh(cn);
            bool upd = (t < len_);
            if (upd) { cst = cn; hst = hn; }
            hl[wb + awr] = (signed char)__float2int_rn(hst * H_SCALE);
        }
        __syncthreads();
        #pragma unroll
        for (int g = 0; g < 4; ++g) xr[g] = xn[g];
    }

    hfin[(size_t)gr * 256 + hh] = f2bf(hst);
}

#define TS 64
#define KT 16
#define LDW (TS + 4)

// qM[512x256] = bf16 h(rows 0..511) @ fp32 M[256x256]
__global__ __launch_bounds__(256)
void gemm_qM_kernel(const unsigned short* __restrict__ hA, const float* __restrict__ B,
                    float* __restrict__ C)
{
    __shared__ float As[KT][LDW];
    __shared__ float Bs[KT][LDW];
    const int tid = threadIdx.x;
    const int tx = tid & 15, ty = tid >> 4;
    const int m0 = blockIdx.x * TS, n0 = blockIdx.y * TS;
    float acc[4][4] = {};
    for (int kk = 0; kk < 256; kk += KT) {
        #pragma unroll
        for (int i = 0; i < 4; ++i) {
            int l = tid + i * 256;
            As[l & 15][l >> 4] = bf2f(hA[(m0 + (l >> 4)) * 256 + kk + (l & 15)]);
            Bs[l >> 6][l & 63] = B[(kk + (l >> 6)) * 256 + n0 + (l & 63)];
        }
        __syncthreads();
        #pragma unroll
        for (int k = 0; k < KT; ++k) {
            float4 a4 = *(const float4*)&As[k][ty * 4];
            float4 b4 = *(const float4*)&Bs[k][tx * 4];
            float av[4] = {a4.x, a4.y, a4.z, a4.w};
            float bv[4] = {b4.x, b4.y, b4.z, b4.w};
            #pragma unroll
            for (int i = 0; i < 4; ++i)
                #pragma unroll
                for (int j = 0; j < 4; ++j)
                    acc[i][j] = fmaf(av[i], bv[j], acc[i][j]);
        }
        __syncthreads();
    }
    #pragma unroll
    for (int i = 0; i < 4; ++i) {
        float4 v = {acc[i][0], acc[i][1], acc[i][2], acc[i][3]};
        *(float4*)&C[(m0 + ty * 4 + i) * 256 + n0 + tx * 4] = v;
    }
}

// D[512x512] = fp32 qM[512x256] @ (bf16 r[512x256])^T
__global__ __launch_bounds__(256)
void gemm_D_kernel(const float* __restrict__ A, const unsigned short* __restrict__ hB,
                   float* __restrict__ C)
{
    __shared__ float As[KT][LDW];
    __shared__ float Bs[KT][LDW];
    const int tid = threadIdx.x;
    const int tx = tid & 15, ty = tid >> 4;
    const int m0 = blockIdx.x * TS, n0 = blockIdx.y * TS;
    float acc[4][4] = {};
    for (int kk = 0; kk < 256; kk += KT) {
        #pragma unroll
        for (int i = 0; i < 4; ++i) {
            int l = tid + i * 256;
            As[l & 15][l >> 4] = A[(m0 + (l >> 4)) * 256 + kk + (l & 15)];
            Bs[l & 15][l >> 4] = bf2f(hB[(n0 + (l >> 4)) * 256 + kk + (l & 15)]);
        }
        __syncthreads();
        #pragma unroll
        for (int k = 0; k < KT; ++k) {
            float4 a4 = *(const float4*)&As[k][ty * 4];
            float4 b4 = *(const float4*)&Bs[k][tx * 4];
            float av[4] = {a4.x, a4.y, a4.z, a4.w};
            float bv[4] = {b4.x, b4.y, b4.z, b4.w};
            #pragma unroll
            for (int i = 0; i < 4; ++i)
                #pragma unroll
                for (int j = 0; j < 4; ++j)
                    acc[i][j] = fmaf(av[i], bv[j], acc[i][j]);
        }
        __syncthreads();
    }
    #pragma unroll
    for (int i = 0; i < 4; ++i) {
        float4 v = {acc[i][0], acc[i][1], acc[i][2], acc[i][3]};
        *(float4*)&C[(m0 + ty * 4 + i) * 512 + n0 + tx * 4] = v;
    }
}

__global__ __launch_bounds__(256)
void loss_kernel(const float* __restrict__ D, const float* __restrict__ wd,
                 float* __restrict__ out)
{
    int idx = blockIdx.x * 256 + threadIdx.x;
    int j = idx & 511;
    float d   = D[idx];
    float pos = D[j * 512 + j];
    float ww  = wd[idx];
    float wp  = wd[j * 512 + j];
    float wn  = fmaxf(0.f, fmaf(ww, frcp(wp), -1.f));
    float v   = fmaxf(0.f, d - pos + wn);
    #pragma unroll
    for (int o = 32; o > 0; o >>= 1) v += __shfl_down(v, o);
    __shared__ float sm[4];
    if ((threadIdx.x & 63) == 0) sm[threadIdx.x >> 6] = v;
    __syncthreads();
    if (threadIdx.x == 0) atomicAdd(out, sm[0] + sm[1] + sm[2] + sm[3]);
}

extern "C" void kernel_launch(void* const* d_in, const int* in_sizes, int n_in,
                              void* d_out, int out_size, void* d_ws, size_t ws_size,
                              hipStream_t stream) {
    const int*   idq  = (const int*)d_in[0];
    const int*   idr  = (const int*)d_in[1];
    const int*   lenq = (const int*)d_in[2];
    const int*   lenr = (const int*)d_in[3];
    const float* wd   = (const float*)d_in[4];
    const float* emb  = (const float*)d_in[5];
    const float* W    = (const float*)d_in[6];
    const float* bias = (const float*)d_in[7];
    const float* p_i  = (const float*)d_in[8];
    const float* p_f  = (const float*)d_in[9];
    const float* p_o  = (const float*)d_in[10];
    const float* Mm   = (const float*)d_in[11];
    float* out = (float*)d_out;

    char* ws = (char*)d_ws;
    unsigned short* X    = (unsigned short*)ws;           // 49*1024*1024 bf16 = 102,760,448 B
    char* p = ws + (size_t)NSTEP * 1048576 * 2;
    unsigned short* hfin = (unsigned short*)p;  p += 1024 * 256 * 2;   // 512 KB
    unsigned short* Wxp  = (unsigned short*)p;  p += 1024 * 256 * 2;   // 512 KB
    signed char*    Wq   = (signed char*)p;     p += 1024 * 256;       // 256 KB
    float* qM = (float*)p;  p += 512 * 256 * 4;                        // 512 KB
    float* D  = (float*)p;  p += 512 * 512 * 4;                        // 1 MB
    int* perm = (int*)p;                                               // 4 KB

    sort_kernel<<<1, 1024, 0, stream>>>(lenq, lenr, perm, out);
    pack_w_kernel<<<dim3(64, 2), 256, 0, stream>>>(W, Wxp, Wq);
    xproj_kernel<<<dim3(196, 4), 512, 0, stream>>>(emb, idq, idr, lenq, lenr,
                                                   perm, Wxp, bias, X);
    lstm_i8_kernel<<<256, 1024, 0, stream>>>(X, Wq, p_i, p_f, p_o,
                                             lenq, lenr, perm, hfin);
    gemm_qM_kernel<<<dim3(8, 4), 256, 0, stream>>>(hfin, Mm, qM);
    gemm_D_kernel<<<dim3(8, 8), 256, 0, stream>>>(qM, hfin + 512 * 256, D);
    loss_kernel<<<1024, 256, 0, stream>>>(D, wd, out);
}